// Round 1
// baseline (1322.704 us; speedup 1.0000x reference)
//
#include <hip/hip_runtime.h>
#include <hip/hip_bf16.h>
#include <math.h>

// TransformerEncoder (Shaw relative attention), MI355X gfx950.
// All GEMMs: C = A @ B^T, A[M,K], B[N,K] row-major, bf16 MFMA 16x16x32, fp32 acc.
// R = pos + typ folded once; V and R also stored transposed so every GEMM is B^T-form.
// This round: m97-structure GEMM (128x128 tile, BK=64, global_load_lds width-16,
// linear LDS) for all 128-divisible shapes; old 128x64 reg-staged kernel kept only
// for the N=64 attention PV/PR GEMMs.

typedef __hip_bfloat16 bf16;
typedef short short8 __attribute__((ext_vector_type(8)));
typedef float f32x4 __attribute__((ext_vector_type(4)));

typedef __attribute__((address_space(1))) const void gvoid;
typedef __attribute__((address_space(3))) void lvoid;

constexpr int Lc = 512;      // sequence length (also S)
constexpr int Bc = 8;        // batch
constexpr int Ec = 1024;     // embed
constexpr int Hc = 16;       // heads
constexpr int HDc = 64;      // head dim
constexpr int NLc = 2;       // layers
constexpr int DFFc = 4096;   // ffn dim
constexpr int LB = Lc * Bc;  // 4096 tokens
constexpr int BHc = Bc * Hc; // 128
constexpr float EPSc = 1e-5f;

__device__ inline unsigned short f2bfu(float f) {
  union { __hip_bfloat16 h; unsigned short u; } cv;
  cv.h = __float2bfloat16(f);
  return cv.u;
}

// ---------------------------------------------------------------------------
// m97-structure GEMM: C[z][M,N] = A[z][M,K] @ B[z][N,K]^T (+bias) (+=C) (gelu)
// tile 128x128, BK=64, 256 threads = 4 waves in a 2x2 grid, acc[4][4]/wave.
// Staging via global_load_lds width 16: LDS dest is wave-uniform base + lane*16,
// global source per-lane (rule #21: both sides linear). M%128==0, N%128==0,
// K%64==0 required; all global rows 16B-aligned (lda/ldb multiples of 8).
// ---------------------------------------------------------------------------
template <bool ACC, bool GELU, bool OBF>
__global__ __launch_bounds__(256) void gemm_bt128(
    int M, int N, int K,
    const bf16* __restrict__ A, int lda, long long sAz,
    const bf16* __restrict__ Bm, int ldb, long long sBz,
    void* __restrict__ Cv, int ldc, long long sCz,
    const float* __restrict__ bias) {
  __shared__ __align__(16) bf16 As[128 * 64];
  __shared__ __align__(16) bf16 Bs[128 * 64];
  const int tid = threadIdx.x;
  const int w = tid >> 6, lane = tid & 63, quad = lane >> 4, lr = lane & 15;
  const int wr = w >> 1, wc = w & 1;
  const int m0 = blockIdx.x * 128, n0 = blockIdx.y * 128;
  const long long z = blockIdx.z;
  A += z * sAz;
  Bm += z * sBz;
  float* Cf = (float*)Cv;
  bf16* Cb = (bf16*)Cv;

  f32x4 acc[4][4];
#pragma unroll
  for (int i = 0; i < 4; i++)
#pragma unroll
    for (int j = 0; j < 4; j++) acc[i][j] = {0.f, 0.f, 0.f, 0.f};

  // staging geometry: 16 chunks of 8 rows x 64 cols; wave w owns chunks w*4..w*4+3.
  // lane covers row chunk*8 + (lane>>3), col 8*(lane&7); LDS dest = chunk*512 elems
  // (wave-uniform) + lane*16B (hardware) == row-major linear. [verified identity]
  const int rA = lane >> 3;
  const int cA = (lane & 7) * 8;

  for (int k0 = 0; k0 < K; k0 += 64) {
#pragma unroll
    for (int t = 0; t < 4; ++t) {
      const int chunk = w * 4 + t;         // uniform per wave
      const int row = chunk * 8 + rA;
      __builtin_amdgcn_global_load_lds(
          (gvoid*)(A + (long long)(m0 + row) * lda + k0 + cA),
          (lvoid*)(As + chunk * 512), 16, 0, 0);
      __builtin_amdgcn_global_load_lds(
          (gvoid*)(Bm + (long long)(n0 + row) * ldb + k0 + cA),
          (lvoid*)(Bs + chunk * 512), 16, 0, 0);
    }
    __syncthreads();  // compiler drains vmcnt(0) before s_barrier
#pragma unroll
    for (int ks = 0; ks < 64; ks += 32) {
      short8 a[4], b[4];
#pragma unroll
      for (int i = 0; i < 4; i++)
        a[i] = *(const short8*)&As[(wr * 64 + i * 16 + lr) * 64 + ks + quad * 8];
#pragma unroll
      for (int j = 0; j < 4; j++)
        b[j] = *(const short8*)&Bs[(wc * 64 + j * 16 + lr) * 64 + ks + quad * 8];
#pragma unroll
      for (int i = 0; i < 4; i++)
#pragma unroll
        for (int j = 0; j < 4; j++)
          acc[i][j] = __builtin_amdgcn_mfma_f32_16x16x32_bf16(a[i], b[j], acc[i][j], 0, 0, 0);
    }
    __syncthreads();
  }

  // epilogue: D row = quad*4+r, col = lane&15 (verified gfx950 C/D layout)
#pragma unroll
  for (int i = 0; i < 4; i++) {
#pragma unroll
    for (int j = 0; j < 4; j++) {
      int col = n0 + wc * 64 + j * 16 + lr;
      float bv = bias ? bias[col] : 0.f;
#pragma unroll
      for (int r = 0; r < 4; r++) {
        int row = m0 + wr * 64 + i * 16 + quad * 4 + r;
        long long off = z * sCz + (long long)row * ldc + col;
        float v = acc[i][j][r] + bv;
        if (ACC) v += Cf[off];
        if (GELU) v = 0.5f * v * (1.f + erff(v * 0.70710678118654752f));
        if (OBF)
          Cb[off] = __float2bfloat16(v);
        else
          Cf[off] = v;
      }
    }
  }
}

// ---------------------------------------------------------------------------
// Legacy 128x64 reg-staged GEMM — kept only for N=64 attention PV/PR shapes.
// ---------------------------------------------------------------------------
template <bool ACC, bool GELU, bool OBF>
__global__ __launch_bounds__(256) void gemm_bt(
    int M, int N, int K,
    const bf16* __restrict__ A, int lda, long long sAz,
    const bf16* __restrict__ Bm, int ldb, long long sBz,
    void* __restrict__ Cv, int ldc, long long sCz,
    const float* __restrict__ bias) {
  __shared__ __align__(16) bf16 As[128 * 72];  // +8 pad: 2-way bank aliasing only (free)
  __shared__ __align__(16) bf16 Bs[64 * 72];
  const int tid = threadIdx.x;
  const int w = tid >> 6, lane = tid & 63, quad = lane >> 4, lr = lane & 15;
  const int m0 = blockIdx.x * 128, n0 = blockIdx.y * 64;
  const long long z = blockIdx.z;
  A += z * sAz;
  Bm += z * sBz;
  float* Cf = (float*)Cv;
  bf16* Cb = (bf16*)Cv;

  f32x4 acc[2][4];
#pragma unroll
  for (int i = 0; i < 2; i++)
#pragma unroll
    for (int j = 0; j < 4; j++) acc[i][j] = {0.f, 0.f, 0.f, 0.f};

  for (int k0 = 0; k0 < K; k0 += 64) {
    // stage A 128x64
#pragma unroll
    for (int i = 0; i < 8; i++) {
      int slot = tid + i * 256;  // 2048 slots
      int r = slot >> 4, c4 = (slot & 15) << 2;
      const bf16* srcp = A + (long long)(m0 + r) * lda + k0 + c4;
      *(ushort4*)&As[r * 72 + c4] = *(const ushort4*)srcp;
    }
    // stage B 64x64
#pragma unroll
    for (int i = 0; i < 4; i++) {
      int slot = tid + i * 256;  // 1024 slots
      int r = slot >> 4, c4 = (slot & 15) << 2;
      const bf16* srcp = Bm + (long long)(n0 + r) * ldb + k0 + c4;
      *(ushort4*)&Bs[r * 72 + c4] = *(const ushort4*)srcp;
    }
    __syncthreads();
#pragma unroll
    for (int ks = 0; ks < 64; ks += 32) {
      short8 a[2], b[4];
#pragma unroll
      for (int i = 0; i < 2; i++)
        a[i] = *(const short8*)&As[(w * 32 + i * 16 + lr) * 72 + ks + quad * 8];
#pragma unroll
      for (int j = 0; j < 4; j++)
        b[j] = *(const short8*)&Bs[(j * 16 + lr) * 72 + ks + quad * 8];
#pragma unroll
      for (int i = 0; i < 2; i++)
#pragma unroll
        for (int j = 0; j < 4; j++)
          acc[i][j] = __builtin_amdgcn_mfma_f32_16x16x32_bf16(a[i], b[j], acc[i][j], 0, 0, 0);
    }
    __syncthreads();
  }

  // epilogue: D row = quad*4+r, col = lane&15 (verified gfx950 C/D layout)
#pragma unroll
  for (int i = 0; i < 2; i++) {
#pragma unroll
    for (int j = 0; j < 4; j++) {
      int col = n0 + j * 16 + lr;
      float bv = bias ? bias[col] : 0.f;
#pragma unroll
      for (int r = 0; r < 4; r++) {
        int row = m0 + w * 32 + i * 16 + quad * 4 + r;
        long long off = z * sCz + (long long)row * ldc + col;
        float v = acc[i][j][r] + bv;
        if (ACC) v += Cf[off];
        if (GELU) v = 0.5f * v * (1.f + erff(v * 0.70710678118654752f));
        if (OBF)
          Cb[off] = __float2bfloat16(v);
        else
          Cf[off] = v;
      }
    }
  }
}

// ---------------------------------------------------------------------------
// prep: fp32 -> bf16 conversion (weights)
// ---------------------------------------------------------------------------
__global__ void cvt_bf16(const float* __restrict__ in, bf16* __restrict__ out, long long n) {
  long long i = (long long)blockIdx.x * 256 + threadIdx.x;
  if (i < n) out[i] = __float2bfloat16(in[i]);
}

// x = src (fp32), xb = bf16(src)
__global__ void init_x(const float* __restrict__ src, float* __restrict__ x, bf16* __restrict__ xb) {
  long long i = (long long)blockIdx.x * 256 + threadIdx.x;
  float v = src[i];
  x[i] = v;
  xb[i] = __float2bfloat16(v);
}

// R = pos + typ -> Rb[l,s,d] bf16 and Rt[l,d,s] bf16. grid (L/64 s-tiles, L), 256 thr
__global__ void prep_R(const float* __restrict__ pos, const float* __restrict__ typ,
                       bf16* __restrict__ Rb, bf16* __restrict__ Rt) {
  __shared__ __align__(16) float Ls[64 * 68];
  int l = blockIdx.y, s0 = blockIdx.x * 64;
  int tid = threadIdx.x;
#pragma unroll
  for (int i = 0; i < 4; i++) {
    int slot = tid + i * 256;
    int r = slot >> 4, c = (slot & 15) << 2;  // r = s offset, c = d
    long long off = (((long long)l) * Lc + s0 + r) * HDc + c;
    float4 a = *(const float4*)&pos[off];
    float4 b = *(const float4*)&typ[off];
    float4 s = {a.x + b.x, a.y + b.y, a.z + b.z, a.w + b.w};
    *(float4*)&Ls[r * 68 + c] = s;
    ushort4 o = {f2bfu(s.x), f2bfu(s.y), f2bfu(s.z), f2bfu(s.w)};
    *(ushort4*)&Rb[off] = o;
  }
  __syncthreads();
#pragma unroll
  for (int i = 0; i < 4; i++) {
    int slot = tid + i * 256;
    int d = slot >> 4, s4 = (slot & 15) << 2;
    ushort4 o = {f2bfu(Ls[(s4 + 0) * 68 + d]), f2bfu(Ls[(s4 + 1) * 68 + d]),
                 f2bfu(Ls[(s4 + 2) * 68 + d]), f2bfu(Ls[(s4 + 3) * 68 + d])};
    *(ushort4*)&Rt[(((long long)l) * HDc + d) * Lc + s0 + s4] = o;
  }
}

// P[L*B, 3E] -> q,k bf16 in [B,H,L,HD]; q scaled by HD^-0.5
__global__ void split_qk(const float* __restrict__ P, bf16* __restrict__ q, bf16* __restrict__ k) {
  long long idx = (long long)blockIdx.x * 256 + threadIdx.x;  // over L*B*E
  int col = idx & (Ec - 1);
  long long row = idx >> 10;  // l*B + b
  int l = (int)(row >> 3), b = (int)(row & 7);
  int h = col >> 6, d = col & 63;
  long long dst = (((long long)(b * Hc + h)) * Lc + l) * HDc + d;
  q[dst] = __float2bfloat16(P[row * 3072 + col] * 0.125f);
  k[dst] = __float2bfloat16(P[row * 3072 + Ec + col]);
}

// P v-part -> vt[b,h,d,l] bf16 via LDS transpose. grid (L/64, BH), 256 thr
__global__ void transpose_v(const float* __restrict__ P, bf16* __restrict__ vt) {
  __shared__ __align__(16) float Ls[64 * 68];
  int bh = blockIdx.y, b = bh >> 4, h = bh & 15;
  int l0 = blockIdx.x * 64;
  int tid = threadIdx.x;
#pragma unroll
  for (int i = 0; i < 4; i++) {
    int slot = tid + i * 256;
    int r = slot >> 4, c = (slot & 15) << 2;  // r = l offset, c = d
    float4 v = *(const float4*)&P[((long long)(l0 + r) * Bc + b) * 3072 + 2 * Ec + h * 64 + c];
    *(float4*)&Ls[r * 68 + c] = v;
  }
  __syncthreads();
#pragma unroll
  for (int i = 0; i < 4; i++) {
    int slot = tid + i * 256;
    int d = slot >> 4, s4 = (slot & 15) << 2;
    ushort4 o = {f2bfu(Ls[(s4 + 0) * 68 + d]), f2bfu(Ls[(s4 + 1) * 68 + d]),
                 f2bfu(Ls[(s4 + 2) * 68 + d]), f2bfu(Ls[(s4 + 3) * 68 + d])};
    *(ushort4*)&vt[(((long long)(b * Hc + h)) * HDc + d) * Lc + l0 + s4] = o;
  }
}

// softmax over rows of 512 fp32 -> bf16 probs IN-PLACE (probs row at bf16 offset
// row*1024, overlapping the same fp32 row). One wave per row, 4 rows/block.
// NOTE: no __restrict__ — S and P genuinely alias.
__global__ __launch_bounds__(256) void softmax_rows(const float* S, bf16* P) {
  int w = threadIdx.x >> 6, lane = threadIdx.x & 63;
  long long row = (long long)blockIdx.x * 4 + w;
  const float* sr = S + row * 512;
  float4 v0 = *(const float4*)(sr + lane * 4);
  float4 v1 = *(const float4*)(sr + 256 + lane * 4);
  float mx = fmaxf(fmaxf(fmaxf(v0.x, v0.y), fmaxf(v0.z, v0.w)),
                   fmaxf(fmaxf(v1.x, v1.y), fmaxf(v1.z, v1.w)));
#pragma unroll
  for (int o = 32; o; o >>= 1) mx = fmaxf(mx, __shfl_xor(mx, o, 64));
  float e[8];
  e[0] = __expf(v0.x - mx); e[1] = __expf(v0.y - mx);
  e[2] = __expf(v0.z - mx); e[3] = __expf(v0.w - mx);
  e[4] = __expf(v1.x - mx); e[5] = __expf(v1.y - mx);
  e[6] = __expf(v1.z - mx); e[7] = __expf(v1.w - mx);
  float sum = e[0] + e[1] + e[2] + e[3] + e[4] + e[5] + e[6] + e[7];
#pragma unroll
  for (int o = 32; o; o >>= 1) sum += __shfl_xor(sum, o, 64);
  float inv = 1.f / sum;
  ushort4 o0 = {f2bfu(e[0] * inv), f2bfu(e[1] * inv), f2bfu(e[2] * inv), f2bfu(e[3] * inv)};
  ushort4 o1 = {f2bfu(e[4] * inv), f2bfu(e[5] * inv), f2bfu(e[6] * inv), f2bfu(e[7] * inv)};
  *(ushort4*)(P + row * 1024 + lane * 4) = o0;
  *(ushort4*)(P + row * 1024 + 256 + lane * 4) = o1;
}

// ao2[B,H,L,HD] fp32 -> aob[(l*B+b), h*64+d] bf16
__global__ void merge_ao(const float* __restrict__ ao2, bf16* __restrict__ aob) {
  long long i = (long long)blockIdx.x * 256 + threadIdx.x;  // over B*H*L*HD
  int d = (int)(i & 63);
  long long t = i >> 6;
  int l = (int)(t & (Lc - 1));
  long long bh = t >> 9;
  int b = (int)(bh >> 4), h = (int)(bh & 15);
  aob[((long long)(l * Bc + b)) * Ec + h * 64 + d] = __float2bfloat16(ao2[i]);
}

// x_out = LN(x + c) * g + be; writes fp32 (outF) and bf16 (outB). one row/block
__global__ __launch_bounds__(256) void add_ln(const float* __restrict__ X, const float* __restrict__ Cin,
                                              const float* __restrict__ g, const float* __restrict__ be,
                                              float* __restrict__ outF, bf16* __restrict__ outB) {
  __shared__ float s_sum[4], s_sq[4];
  long long row = blockIdx.x;
  int tid = threadIdx.x;
  float4 xv = *(const float4*)&X[row * Ec + tid * 4];
  float4 cv = *(const float4*)&Cin[row * Ec + tid * 4];
  float v[4] = {xv.x + cv.x, xv.y + cv.y, xv.z + cv.z, xv.w + cv.w};
  float sm = v[0] + v[1] + v[2] + v[3];
  float sq = v[0] * v[0] + v[1] * v[1] + v[2] * v[2] + v[3] * v[3];
#pragma unroll
  for (int o = 32; o; o >>= 1) {
    sm += __shfl_xor(sm, o, 64);
    sq += __shfl_xor(sq, o, 64);
  }
  int w = tid >> 6, lane = tid & 63;
  if (lane == 0) {
    s_sum[w] = sm;
    s_sq[w] = sq;
  }
  __syncthreads();
  sm = s_sum[0] + s_sum[1] + s_sum[2] + s_sum[3];
  sq = s_sq[0] + s_sq[1] + s_sq[2] + s_sq[3];
  float mean = sm * (1.f / Ec);
  float var = sq * (1.f / Ec) - mean * mean;
  float rs = rsqrtf(var + EPSc);
#pragma unroll
  for (int e = 0; e < 4; e++) {
    int n = tid * 4 + e;
    float o = (v[e] - mean) * rs * g[n] + be[n];
    outF[row * Ec + n] = o;
    outB[row * Ec + n] = __float2bfloat16(o);
  }
}

// ---------------------------------------------------------------------------
// Workspace need (bytes), all 256B-aligned blocks:
//   U (P 50MB / scores 134MB+probs-in-place / hb 34MB):  134217728
//   x 16777216, xb 8388608, q 8388608, k 8388608, vt 8388608,
//   ao2c1 16777216, aob 8388608, Rb 33554432, Rt 33554432,
//   wib 12582912, wob 4194304, w1b 16777216, w2b 16777216
// total = 327155712 (312 MiB)
// ---------------------------------------------------------------------------
static constexpr size_t WS_NEED = 327155712;

// Fallback workspace, allocated ONCE at dlopen time (outside kernel_launch and
// outside graph capture). Used only if the harness workspace is too small.
struct GlobalWs {
  void* p = nullptr;
  GlobalWs() {
    if (hipMalloc(&p, WS_NEED) != hipSuccess) p = nullptr;
  }
};
static GlobalWs g_ws;

extern "C" void kernel_launch(void* const* d_in, const int* in_sizes, int n_in,
                              void* d_out, int out_size, void* d_ws, size_t ws_size,
                              hipStream_t stream) {
  const float* src = (const float*)d_in[0];
  const float* pos = (const float*)d_in[1];
  const float* typ = (const float*)d_in[2];
  const float* Wi = (const float*)d_in[3];
  const float* bi = (const float*)d_in[4];
  const float* Wo = (const float*)d_in[5];
  const float* bo = (const float*)d_in[6];
  const float* W1 = (const float*)d_in[7];
  const float* b1 = (const float*)d_in[8];
  const float* W2 = (const float*)d_in[9];
  const float* b2 = (const float*)d_in[10];
  const float* g1 = (const float*)d_in[11];
  const float* be1 = (const float*)d_in[12];
  const float* g2 = (const float*)d_in[13];
  const float* be2 = (const float*)d_in[14];
  float* out = (float*)d_out;
  (void)in_sizes; (void)n_in; (void)out_size;

  // Deterministic workspace choice (same every call): harness ws if big enough,
  // else the static fallback.
  char* wp = (ws_size >= WS_NEED) ? (char*)d_ws : (char*)g_ws.p;
  if (!wp) wp = (char*)d_ws;  // last resort
  auto alloc = [&](size_t bytes) {
    char* r = wp;
    wp += (bytes + 255) & ~(size_t)255;
    return r;
  };

  // Union region: P (QKV out fp32) -> scores fp32 (+ probs bf16 in-place) -> hb bf16
  char* U = alloc((size_t)BHc * Lc * Lc * 4);               // 134 MB
  float* P = (float*)U;
  float* scores = (float*)U;
  bf16* probs = (bf16*)U;                                   // row l at bf16 offset row*1024
  bf16* hb = (bf16*)U;

  float* x = (float*)alloc((size_t)LB * Ec * 4);            // residual fp32
  bf16* xb = (bf16*)alloc((size_t)LB * Ec * 2);             // LN'd bf16 for GEMMs
  bf16* q = (bf16*)alloc((size_t)BHc * Lc * HDc * 2);       // [B,H,L,HD]
  bf16* k = (bf16*)alloc((size_t)BHc * Lc * HDc * 2);
  bf16* vt = (bf16*)alloc((size_t)BHc * HDc * Lc * 2);      // [B,H,HD,L]
  float* ao2 = (float*)alloc((size_t)BHc * Lc * HDc * 4);   // attn out [B,H,L,HD]; aliased as c1
  float* c1 = ao2;                                          // proj / ffn2 out fp32 (disjoint lifetime)
  bf16* aob = (bf16*)alloc((size_t)LB * Ec * 2);            // merged [L*B, E] bf16
  bf16* Rb = (bf16*)alloc((size_t)Lc * Lc * HDc * 2);       // R[l,s,d]
  bf16* Rt = (bf16*)alloc((size_t)Lc * HDc * Lc * 2);       // R^T[l,d,s]
  bf16* wib = (bf16*)alloc((size_t)NLc * 3 * Ec * Ec * 2);
  bf16* wob = (bf16*)alloc((size_t)NLc * Ec * Ec * 2);
  bf16* w1b = (bf16*)alloc((size_t)NLc * DFFc * Ec * 2);
  bf16* w2b = (bf16*)alloc((size_t)NLc * Ec * DFFc * 2);

  // ---- prep
  {
    long long n;
    n = (long long)NLc * 3 * Ec * Ec;
    cvt_bf16<<<(int)((n + 255) / 256), 256, 0, stream>>>(Wi, wib, n);
    n = (long long)NLc * Ec * Ec;
    cvt_bf16<<<(int)((n + 255) / 256), 256, 0, stream>>>(Wo, wob, n);
    n = (long long)NLc * DFFc * Ec;
    cvt_bf16<<<(int)((n + 255) / 256), 256, 0, stream>>>(W1, w1b, n);
    n = (long long)NLc * Ec * DFFc;
    cvt_bf16<<<(int)((n + 255) / 256), 256, 0, stream>>>(W2, w2b, n);
  }
  prep_R<<<dim3(Lc / 64, Lc), 256, 0, stream>>>(pos, typ, Rb, Rt);
  init_x<<<LB * Ec / 256, 256, 0, stream>>>(src, x, xb);

  for (int i = 0; i < NLc; i++) {
    const bf16* Wi_b = wib + (size_t)i * 3 * Ec * Ec;
    const bf16* Wo_b = wob + (size_t)i * Ec * Ec;
    const bf16* W1_b = w1b + (size_t)i * DFFc * Ec;
    const bf16* W2_b = w2b + (size_t)i * Ec * DFFc;

    // QKV projection: P = xb @ Wi^T + bi   [4096, 3072]
    gemm_bt128<false, false, false><<<dim3(LB / 128, 3 * Ec / 128, 1), 256, 0, stream>>>(
        LB, 3 * Ec, Ec, xb, Ec, 0, Wi_b, Ec, 0, P, 3 * Ec, 0, bi + (size_t)i * 3 * Ec);
    split_qk<<<LB * Ec / 256, 256, 0, stream>>>(P, q, k);
    transpose_v<<<dim3(Lc / 64, BHc), 256, 0, stream>>>(P, vt);

    // scores = q @ k^T  (batched over bh)   [P dead from here]
    gemm_bt128<false, false, false><<<dim3(Lc / 128, Lc / 128, BHc), 256, 0, stream>>>(
        Lc, Lc, HDc, q, HDc, (long long)Lc * HDc, k, HDc, (long long)Lc * HDc,
        scores, Lc, (long long)Lc * Lc, nullptr);
    // scores += q_l @ R_l^T  (batched over l)
    gemm_bt128<true, false, false><<<dim3(1, Lc / 128, Lc), 256, 0, stream>>>(
        BHc, Lc, HDc, q, Lc * HDc, (long long)HDc, Rb, HDc, (long long)Lc * HDc,
        scores, Lc * Lc, (long long)Lc, nullptr);

    // softmax, probs bf16 in-place over scores (row stride 1024 bf16 elements)
    softmax_rows<<<BHc * Lc / 4, 256, 0, stream>>>(scores, probs);

    // ao2 = probs @ v  (v^T stored => B^T-form; batched over bh)  [N=64 -> legacy kernel]
    gemm_bt<false, false, false><<<dim3(Lc / 128, 1, BHc), 256, 0, stream>>>(
        Lc, HDc, Lc, probs, 1024, (long long)Lc * 1024, vt, Lc, (long long)HDc * Lc,
        ao2, HDc, (long long)Lc * HDc, nullptr);
    // ao2 += probs_l @ R_l  (R^T stored => B^T-form; batched over l)  [N=64 -> legacy kernel]
    gemm_bt<true, false, false><<<dim3(1, 1, Lc), 256, 0, stream>>>(
        BHc, HDc, Lc, probs, Lc * 1024, (long long)1024, Rt, Lc, (long long)HDc * Lc,
        ao2, Lc * HDc, (long long)HDc, nullptr);

    merge_ao<<<BHc * Lc * HDc / 256, 256, 0, stream>>>(ao2, aob);

    // output projection: c1 = aob @ Wo^T + bo   [ao2 dead; c1 aliases it]
    gemm_bt128<false, false, false><<<dim3(LB / 128, Ec / 128, 1), 256, 0, stream>>>(
        LB, Ec, Ec, aob, Ec, 0, Wo_b, Ec, 0, c1, Ec, 0, bo + (size_t)i * Ec);
    add_ln<<<LB, 256, 0, stream>>>(x, c1, g1 + (size_t)i * Ec, be1 + (size_t)i * Ec, x, xb);

    // ffn1: hb = gelu(xb @ W1^T + b1)  bf16 out   [probs dead; hb aliases U]
    gemm_bt128<false, true, true><<<dim3(LB / 128, DFFc / 128, 1), 256, 0, stream>>>(
        LB, DFFc, Ec, xb, Ec, 0, W1_b, Ec, 0, hb, DFFc, 0, b1 + (size_t)i * DFFc);
    // ffn2: c1 = hb @ W2^T + b2
    gemm_bt128<false, false, false><<<dim3(LB / 128, Ec / 128, 1), 256, 0, stream>>>(
        LB, Ec, DFFc, hb, DFFc, 0, W2_b, DFFc, 0, c1, Ec, 0, b2 + (size_t)i * Ec);

    float* outF = (i == NLc - 1) ? out : x;
    add_ln<<<LB, 256, 0, stream>>>(x, c1, g2 + (size_t)i * Ec, be2 + (size_t)i * Ec, outF, xb);
  }
}

// Round 3
// 1288.980 us; speedup vs baseline: 1.0262x; 1.0262x over previous
//
#include <hip/hip_runtime.h>
#include <hip/hip_bf16.h>
#include <math.h>

// TransformerEncoder (Shaw relative attention), MI355X gfx950.
// All GEMMs: C = A @ B^T, A[M,K], B[N,K] row-major, bf16 MFMA 16x16x32, fp32 acc.
// R = pos + typ folded once; V and R also stored transposed so every GEMM is B^T-form.
// This round: T3-minimum double-buffered GEMM with COMPILER-managed barriers only
// (__syncthreads once per K-step, placed AFTER compute so the vmcnt(0) drain the
// compiler emits before s_barrier lands after the MFMA work). No inline asm, no
// raw s_barrier — de-risked after round-2 container failure. Attention GEMMs use
// the round-0 legacy 128x64 reg-staged kernel (padded LDS, 2-way conflicts).

typedef __hip_bfloat16 bf16;
typedef short short8 __attribute__((ext_vector_type(8)));
typedef float f32x4 __attribute__((ext_vector_type(4)));

typedef __attribute__((address_space(1))) const void gvoid;
typedef __attribute__((address_space(3))) void lvoid;

constexpr int Lc = 512;      // sequence length (also S)
constexpr int Bc = 8;        // batch
constexpr int Ec = 1024;     // embed
constexpr int Hc = 16;       // heads
constexpr int HDc = 64;      // head dim
constexpr int NLc = 2;       // layers
constexpr int DFFc = 4096;   // ffn dim
constexpr int LB = Lc * Bc;  // 4096 tokens
constexpr int BHc = Bc * Hc; // 128
constexpr float EPSc = 1e-5f;

__device__ inline unsigned short f2bfu(float f) {
  union { __hip_bfloat16 h; unsigned short u; } cv;
  cv.h = __float2bfloat16(f);
  return cv.u;
}

// ---------------------------------------------------------------------------
// Double-buffered 2-phase GEMM: C[z][M,N] = A[z][M,K] @ B[z][N,K]^T
// (+bias)(+=C)(gelu). tile 128x128, BK=64, 256 threads = 4 waves (2x2),
// acc[4][4]/wave. Per K-step: STAGE(next buf) issued FIRST, then ds_read+MFMA
// on current buf, then ONE __syncthreads — whose compiler-emitted
// vmcnt(0)+lgkmcnt(0) drain therefore sits AFTER the MFMA work, overlapping the
// next tile's HBM latency with compute. Buffer overwritten at iter t+1 was last
// read at iter t, fenced by iter t's barrier.
// M%128==0, N%128==0, K%64==0; rows 16B-aligned.
// ---------------------------------------------------------------------------
template <bool ACC, bool GELU, bool OBF>
__global__ __launch_bounds__(256) void gemm_bt128d(
    int M, int N, int K,
    const bf16* __restrict__ A, int lda, long long sAz,
    const bf16* __restrict__ Bm, int ldb, long long sBz,
    void* __restrict__ Cv, int ldc, long long sCz,
    const float* __restrict__ bias) {
  __shared__ __align__(16) bf16 As[2 * 128 * 64];
  __shared__ __align__(16) bf16 Bs[2 * 128 * 64];
  const int tid = threadIdx.x;
  const int w = tid >> 6, lane = tid & 63, quad = lane >> 4, lr = lane & 15;
  const int wr = w >> 1, wc = w & 1;
  const int m0 = blockIdx.x * 128, n0 = blockIdx.y * 128;
  const long long z = blockIdx.z;
  A += z * sAz;
  Bm += z * sBz;
  float* Cf = (float*)Cv;
  bf16* Cb = (bf16*)Cv;

  f32x4 acc[4][4];
#pragma unroll
  for (int i = 0; i < 4; i++)
#pragma unroll
    for (int j = 0; j < 4; j++) acc[i][j] = {0.f, 0.f, 0.f, 0.f};

  // staging geometry: 16 chunks of 8 rows x 64 cols per matrix; wave w owns
  // chunks w*4..w*4+3. lane covers row chunk*8+(lane>>3), col 8*(lane&7);
  // LDS dest = chunk*512 elems (wave-uniform) + lane*16B == row-major linear.
  const int rA = lane >> 3;
  const int cA = (lane & 7) * 8;

  auto STAGE = [&](int buf, int kt) {
    const int k0 = kt << 6;
#pragma unroll
    for (int t = 0; t < 4; ++t) {
      const int chunk = w * 4 + t;  // uniform per wave
      const int row = chunk * 8 + rA;
      __builtin_amdgcn_global_load_lds(
          (gvoid*)(A + (long long)(m0 + row) * lda + k0 + cA),
          (lvoid*)(As + buf * 8192 + chunk * 512), 16, 0, 0);
      __builtin_amdgcn_global_load_lds(
          (gvoid*)(Bm + (long long)(n0 + row) * ldb + k0 + cA),
          (lvoid*)(Bs + buf * 8192 + chunk * 512), 16, 0, 0);
    }
  };

  auto COMPUTE = [&](int buf) {
    const bf16* Ab = As + buf * 8192;
    const bf16* Bb = Bs + buf * 8192;
#pragma unroll
    for (int ks = 0; ks < 64; ks += 32) {
      short8 a[4], b[4];
#pragma unroll
      for (int i = 0; i < 4; i++)
        a[i] = *(const short8*)&Ab[(wr * 64 + i * 16 + lr) * 64 + ks + quad * 8];
#pragma unroll
      for (int j = 0; j < 4; j++)
        b[j] = *(const short8*)&Bb[(wc * 64 + j * 16 + lr) * 64 + ks + quad * 8];
#pragma unroll
      for (int i = 0; i < 4; i++)
#pragma unroll
        for (int j = 0; j < 4; j++)
          acc[i][j] = __builtin_amdgcn_mfma_f32_16x16x32_bf16(a[i], b[j], acc[i][j], 0, 0, 0);
    }
  };

  const int nt = K >> 6;
  // prologue: stage tile 0; barrier (drains vmcnt(0))
  STAGE(0, 0);
  __syncthreads();

  int cur = 0;
  for (int t = 0; t < nt - 1; ++t) {
    STAGE(cur ^ 1, t + 1);                // issue next tile's loads FIRST
    __builtin_amdgcn_sched_barrier(0);    // pin issue order (compile-time only)
    COMPUTE(cur);                         // MFMA on current buf hides load latency
    __syncthreads();                      // compiler drains vmcnt/lgkm AFTER compute
    cur ^= 1;
  }
  COMPUTE(cur);  // last tile, no prefetch

  // epilogue: D row = quad*4+r, col = lane&15 (verified gfx950 C/D layout)
#pragma unroll
  for (int i = 0; i < 4; i++) {
#pragma unroll
    for (int j = 0; j < 4; j++) {
      int col = n0 + wc * 64 + j * 16 + lr;
      float bv = bias ? bias[col] : 0.f;
#pragma unroll
      for (int r = 0; r < 4; r++) {
        int row = m0 + wr * 64 + i * 16 + quad * 4 + r;
        long long off = z * sCz + (long long)row * ldc + col;
        float v = acc[i][j][r] + bv;
        if (ACC) v += Cf[off];
        if (GELU) v = 0.5f * v * (1.f + erff(v * 0.70710678118654752f));
        if (OBF)
          Cb[off] = __float2bfloat16(v);
        else
          Cf[off] = v;
      }
    }
  }
}

// ---------------------------------------------------------------------------
// Legacy 128x64 reg-staged GEMM (padded LDS, 2-way conflicts) — attention GEMMs.
// ---------------------------------------------------------------------------
template <bool ACC, bool GELU, bool OBF>
__global__ __launch_bounds__(256) void gemm_bt(
    int M, int N, int K,
    const bf16* __restrict__ A, int lda, long long sAz,
    const bf16* __restrict__ Bm, int ldb, long long sBz,
    void* __restrict__ Cv, int ldc, long long sCz,
    const float* __restrict__ bias) {
  __shared__ __align__(16) bf16 As[128 * 72];  // +8 pad: 2-way bank aliasing only (free)
  __shared__ __align__(16) bf16 Bs[64 * 72];
  const int tid = threadIdx.x;
  const int w = tid >> 6, lane = tid & 63, quad = lane >> 4, lr = lane & 15;
  const int m0 = blockIdx.x * 128, n0 = blockIdx.y * 64;
  const long long z = blockIdx.z;
  A += z * sAz;
  Bm += z * sBz;
  float* Cf = (float*)Cv;
  bf16* Cb = (bf16*)Cv;

  f32x4 acc[2][4];
#pragma unroll
  for (int i = 0; i < 2; i++)
#pragma unroll
    for (int j = 0; j < 4; j++) acc[i][j] = {0.f, 0.f, 0.f, 0.f};

  for (int k0 = 0; k0 < K; k0 += 64) {
    // stage A 128x64
#pragma unroll
    for (int i = 0; i < 8; i++) {
      int slot = tid + i * 256;  // 2048 slots
      int r = slot >> 4, c4 = (slot & 15) << 2;
      const bf16* srcp = A + (long long)(m0 + r) * lda + k0 + c4;
      *(ushort4*)&As[r * 72 + c4] = *(const ushort4*)srcp;
    }
    // stage B 64x64
#pragma unroll
    for (int i = 0; i < 4; i++) {
      int slot = tid + i * 256;  // 1024 slots
      int r = slot >> 4, c4 = (slot & 15) << 2;
      const bf16* srcp = Bm + (long long)(n0 + r) * ldb + k0 + c4;
      *(ushort4*)&Bs[r * 72 + c4] = *(const ushort4*)srcp;
    }
    __syncthreads();
#pragma unroll
    for (int ks = 0; ks < 64; ks += 32) {
      short8 a[2], b[4];
#pragma unroll
      for (int i = 0; i < 2; i++)
        a[i] = *(const short8*)&As[(w * 32 + i * 16 + lr) * 72 + ks + quad * 8];
#pragma unroll
      for (int j = 0; j < 4; j++)
        b[j] = *(const short8*)&Bs[(j * 16 + lr) * 72 + ks + quad * 8];
#pragma unroll
      for (int i = 0; i < 2; i++)
#pragma unroll
        for (int j = 0; j < 4; j++)
          acc[i][j] = __builtin_amdgcn_mfma_f32_16x16x32_bf16(a[i], b[j], acc[i][j], 0, 0, 0);
    }
    __syncthreads();
  }

  // epilogue: D row = quad*4+r, col = lane&15 (verified gfx950 C/D layout)
#pragma unroll
  for (int i = 0; i < 2; i++) {
#pragma unroll
    for (int j = 0; j < 4; j++) {
      int col = n0 + j * 16 + lr;
      float bv = bias ? bias[col] : 0.f;
#pragma unroll
      for (int r = 0; r < 4; r++) {
        int row = m0 + w * 32 + i * 16 + quad * 4 + r;
        long long off = z * sCz + (long long)row * ldc + col;
        float v = acc[i][j][r] + bv;
        if (ACC) v += Cf[off];
        if (GELU) v = 0.5f * v * (1.f + erff(v * 0.70710678118654752f));
        if (OBF)
          Cb[off] = __float2bfloat16(v);
        else
          Cf[off] = v;
      }
    }
  }
}

// ---------------------------------------------------------------------------
// prep: fp32 -> bf16 conversion (weights)
// ---------------------------------------------------------------------------
__global__ void cvt_bf16(const float* __restrict__ in, bf16* __restrict__ out, long long n) {
  long long i = (long long)blockIdx.x * 256 + threadIdx.x;
  if (i < n) out[i] = __float2bfloat16(in[i]);
}

// x = src (fp32), xb = bf16(src)
__global__ void init_x(const float* __restrict__ src, float* __restrict__ x, bf16* __restrict__ xb) {
  long long i = (long long)blockIdx.x * 256 + threadIdx.x;
  float v = src[i];
  x[i] = v;
  xb[i] = __float2bfloat16(v);
}

// R = pos + typ -> Rb[l,s,d] bf16 and Rt[l,d,s] bf16. grid (L/64 s-tiles, L), 256 thr
__global__ void prep_R(const float* __restrict__ pos, const float* __restrict__ typ,
                       bf16* __restrict__ Rb, bf16* __restrict__ Rt) {
  __shared__ __align__(16) float Ls[64 * 68];
  int l = blockIdx.y, s0 = blockIdx.x * 64;
  int tid = threadIdx.x;
#pragma unroll
  for (int i = 0; i < 4; i++) {
    int slot = tid + i * 256;
    int r = slot >> 4, c = (slot & 15) << 2;  // r = s offset, c = d
    long long off = (((long long)l) * Lc + s0 + r) * HDc + c;
    float4 a = *(const float4*)&pos[off];
    float4 b = *(const float4*)&typ[off];
    float4 s = {a.x + b.x, a.y + b.y, a.z + b.z, a.w + b.w};
    *(float4*)&Ls[r * 68 + c] = s;
    ushort4 o = {f2bfu(s.x), f2bfu(s.y), f2bfu(s.z), f2bfu(s.w)};
    *(ushort4*)&Rb[off] = o;
  }
  __syncthreads();
#pragma unroll
  for (int i = 0; i < 4; i++) {
    int slot = tid + i * 256;
    int d = slot >> 4, s4 = (slot & 15) << 2;
    ushort4 o = {f2bfu(Ls[(s4 + 0) * 68 + d]), f2bfu(Ls[(s4 + 1) * 68 + d]),
                 f2bfu(Ls[(s4 + 2) * 68 + d]), f2bfu(Ls[(s4 + 3) * 68 + d])};
    *(ushort4*)&Rt[(((long long)l) * HDc + d) * Lc + s0 + s4] = o;
  }
}

// P[L*B, 3E] -> q,k bf16 in [B,H,L,HD]; q scaled by HD^-0.5
__global__ void split_qk(const float* __restrict__ P, bf16* __restrict__ q, bf16* __restrict__ k) {
  long long idx = (long long)blockIdx.x * 256 + threadIdx.x;  // over L*B*E
  int col = idx & (Ec - 1);
  long long row = idx >> 10;  // l*B + b
  int l = (int)(row >> 3), b = (int)(row & 7);
  int h = col >> 6, d = col & 63;
  long long dst = (((long long)(b * Hc + h)) * Lc + l) * HDc + d;
  q[dst] = __float2bfloat16(P[row * 3072 + col] * 0.125f);
  k[dst] = __float2bfloat16(P[row * 3072 + Ec + col]);
}

// P v-part -> vt[b,h,d,l] bf16 via LDS transpose. grid (L/64, BH), 256 thr
__global__ void transpose_v(const float* __restrict__ P, bf16* __restrict__ vt) {
  __shared__ __align__(16) float Ls[64 * 68];
  int bh = blockIdx.y, b = bh >> 4, h = bh & 15;
  int l0 = blockIdx.x * 64;
  int tid = threadIdx.x;
#pragma unroll
  for (int i = 0; i < 4; i++) {
    int slot = tid + i * 256;
    int r = slot >> 4, c = (slot & 15) << 2;  // r = l offset, c = d
    float4 v = *(const float4*)&P[((long long)(l0 + r) * Bc + b) * 3072 + 2 * Ec + h * 64 + c];
    *(float4*)&Ls[r * 68 + c] = v;
  }
  __syncthreads();
#pragma unroll
  for (int i = 0; i < 4; i++) {
    int slot = tid + i * 256;
    int d = slot >> 4, s4 = (slot & 15) << 2;
    ushort4 o = {f2bfu(Ls[(s4 + 0) * 68 + d]), f2bfu(Ls[(s4 + 1) * 68 + d]),
                 f2bfu(Ls[(s4 + 2) * 68 + d]), f2bfu(Ls[(s4 + 3) * 68 + d])};
    *(ushort4*)&vt[(((long long)(b * Hc + h)) * HDc + d) * Lc + l0 + s4] = o;
  }
}

// softmax over rows of 512 fp32 -> bf16 probs IN-PLACE (probs row at bf16 offset
// row*1024, overlapping the same fp32 row). One wave per row, 4 rows/block.
// NOTE: no __restrict__ — S and P genuinely alias.
__global__ __launch_bounds__(256) void softmax_rows(const float* S, bf16* P) {
  int w = threadIdx.x >> 6, lane = threadIdx.x & 63;
  long long row = (long long)blockIdx.x * 4 + w;
  const float* sr = S + row * 512;
  float4 v0 = *(const float4*)(sr + lane * 4);
  float4 v1 = *(const float4*)(sr + 256 + lane * 4);
  float mx = fmaxf(fmaxf(fmaxf(v0.x, v0.y), fmaxf(v0.z, v0.w)),
                   fmaxf(fmaxf(v1.x, v1.y), fmaxf(v1.z, v1.w)));
#pragma unroll
  for (int o = 32; o; o >>= 1) mx = fmaxf(mx, __shfl_xor(mx, o, 64));
  float e[8];
  e[0] = __expf(v0.x - mx); e[1] = __expf(v0.y - mx);
  e[2] = __expf(v0.z - mx); e[3] = __expf(v0.w - mx);
  e[4] = __expf(v1.x - mx); e[5] = __expf(v1.y - mx);
  e[6] = __expf(v1.z - mx); e[7] = __expf(v1.w - mx);
  float sum = e[0] + e[1] + e[2] + e[3] + e[4] + e[5] + e[6] + e[7];
#pragma unroll
  for (int o = 32; o; o >>= 1) sum += __shfl_xor(sum, o, 64);
  float inv = 1.f / sum;
  ushort4 o0 = {f2bfu(e[0] * inv), f2bfu(e[1] * inv), f2bfu(e[2] * inv), f2bfu(e[3] * inv)};
  ushort4 o1 = {f2bfu(e[4] * inv), f2bfu(e[5] * inv), f2bfu(e[6] * inv), f2bfu(e[7] * inv)};
  *(ushort4*)(P + row * 1024 + lane * 4) = o0;
  *(ushort4*)(P + row * 1024 + 256 + lane * 4) = o1;
}

// ao2[B,H,L,HD] fp32 -> aob[(l*B+b), h*64+d] bf16
__global__ void merge_ao(const float* __restrict__ ao2, bf16* __restrict__ aob) {
  long long i = (long long)blockIdx.x * 256 + threadIdx.x;  // over B*H*L*HD
  int d = (int)(i & 63);
  long long t = i >> 6;
  int l = (int)(t & (Lc - 1));
  long long bh = t >> 9;
  int b = (int)(bh >> 4), h = (int)(bh & 15);
  aob[((long long)(l * Bc + b)) * Ec + h * 64 + d] = __float2bfloat16(ao2[i]);
}

// x_out = LN(x + c) * g + be; writes fp32 (outF) and bf16 (outB). one row/block
__global__ __launch_bounds__(256) void add_ln(const float* __restrict__ X, const float* __restrict__ Cin,
                                              const float* __restrict__ g, const float* __restrict__ be,
                                              float* __restrict__ outF, bf16* __restrict__ outB) {
  __shared__ float s_sum[4], s_sq[4];
  long long row = blockIdx.x;
  int tid = threadIdx.x;
  float4 xv = *(const float4*)&X[row * Ec + tid * 4];
  float4 cv = *(const float4*)&Cin[row * Ec + tid * 4];
  float v[4] = {xv.x + cv.x, xv.y + cv.y, xv.z + cv.z, xv.w + cv.w};
  float sm = v[0] + v[1] + v[2] + v[3];
  float sq = v[0] * v[0] + v[1] * v[1] + v[2] * v[2] + v[3] * v[3];
#pragma unroll
  for (int o = 32; o; o >>= 1) {
    sm += __shfl_xor(sm, o, 64);
    sq += __shfl_xor(sq, o, 64);
  }
  int w = tid >> 6, lane = tid & 63;
  if (lane == 0) {
    s_sum[w] = sm;
    s_sq[w] = sq;
  }
  __syncthreads();
  sm = s_sum[0] + s_sum[1] + s_sum[2] + s_sum[3];
  sq = s_sq[0] + s_sq[1] + s_sq[2] + s_sq[3];
  float mean = sm * (1.f / Ec);
  float var = sq * (1.f / Ec) - mean * mean;
  float rs = rsqrtf(var + EPSc);
#pragma unroll
  for (int e = 0; e < 4; e++) {
    int n = tid * 4 + e;
    float o = (v[e] - mean) * rs * g[n] + be[n];
    outF[row * Ec + n] = o;
    outB[row * Ec + n] = __float2bfloat16(o);
  }
}

// ---------------------------------------------------------------------------
// Workspace need (bytes), all 256B-aligned blocks:
//   U (P 50MB / scores 134MB+probs-in-place / hb 34MB):  134217728
//   x 16777216, xb 8388608, q 8388608, k 8388608, vt 8388608,
//   ao2c1 16777216, aob 8388608, Rb 33554432, Rt 33554432,
//   wib 12582912, wob 4194304, w1b 16777216, w2b 16777216
// total = 327155712 (312 MiB)
// ---------------------------------------------------------------------------
static constexpr size_t WS_NEED = 327155712;

// Fallback workspace, allocated ONCE at dlopen time (outside kernel_launch and
// outside graph capture). Used only if the harness workspace is too small.
struct GlobalWs {
  void* p = nullptr;
  GlobalWs() {
    if (hipMalloc(&p, WS_NEED) != hipSuccess) p = nullptr;
  }
};
static GlobalWs g_ws;

extern "C" void kernel_launch(void* const* d_in, const int* in_sizes, int n_in,
                              void* d_out, int out_size, void* d_ws, size_t ws_size,
                              hipStream_t stream) {
  const float* src = (const float*)d_in[0];
  const float* pos = (const float*)d_in[1];
  const float* typ = (const float*)d_in[2];
  const float* Wi = (const float*)d_in[3];
  const float* bi = (const float*)d_in[4];
  const float* Wo = (const float*)d_in[5];
  const float* bo = (const float*)d_in[6];
  const float* W1 = (const float*)d_in[7];
  const float* b1 = (const float*)d_in[8];
  const float* W2 = (const float*)d_in[9];
  const float* b2 = (const float*)d_in[10];
  const float* g1 = (const float*)d_in[11];
  const float* be1 = (const float*)d_in[12];
  const float* g2 = (const float*)d_in[13];
  const float* be2 = (const float*)d_in[14];
  float* out = (float*)d_out;
  (void)in_sizes; (void)n_in; (void)out_size;

  // Deterministic workspace choice (same every call): harness ws if big enough,
  // else the static fallback.
  char* wp = (ws_size >= WS_NEED) ? (char*)d_ws : (char*)g_ws.p;
  if (!wp) wp = (char*)d_ws;  // last resort
  auto alloc = [&](size_t bytes) {
    char* r = wp;
    wp += (bytes + 255) & ~(size_t)255;
    return r;
  };

  // Union region: P (QKV out fp32) -> scores fp32 (+ probs bf16 in-place) -> hb bf16
  char* U = alloc((size_t)BHc * Lc * Lc * 4);               // 134 MB
  float* P = (float*)U;
  float* scores = (float*)U;
  bf16* probs = (bf16*)U;                                   // row l at bf16 offset row*1024
  bf16* hb = (bf16*)U;

  float* x = (float*)alloc((size_t)LB * Ec * 4);            // residual fp32
  bf16* xb = (bf16*)alloc((size_t)LB * Ec * 2);             // LN'd bf16 for GEMMs
  bf16* q = (bf16*)alloc((size_t)BHc * Lc * HDc * 2);       // [B,H,L,HD]
  bf16* k = (bf16*)alloc((size_t)BHc * Lc * HDc * 2);
  bf16* vt = (bf16*)alloc((size_t)BHc * HDc * Lc * 2);      // [B,H,HD,L]
  float* ao2 = (float*)alloc((size_t)BHc * Lc * HDc * 4);   // attn out [B,H,L,HD]; aliased as c1
  float* c1 = ao2;                                          // proj / ffn2 out fp32 (disjoint lifetime)
  bf16* aob = (bf16*)alloc((size_t)LB * Ec * 2);            // merged [L*B, E] bf16
  bf16* Rb = (bf16*)alloc((size_t)Lc * Lc * HDc * 2);       // R[l,s,d]
  bf16* Rt = (bf16*)alloc((size_t)Lc * HDc * Lc * 2);       // R^T[l,d,s]
  bf16* wib = (bf16*)alloc((size_t)NLc * 3 * Ec * Ec * 2);
  bf16* wob = (bf16*)alloc((size_t)NLc * Ec * Ec * 2);
  bf16* w1b = (bf16*)alloc((size_t)NLc * DFFc * Ec * 2);
  bf16* w2b = (bf16*)alloc((size_t)NLc * Ec * DFFc * 2);

  // ---- prep
  {
    long long n;
    n = (long long)NLc * 3 * Ec * Ec;
    cvt_bf16<<<(int)((n + 255) / 256), 256, 0, stream>>>(Wi, wib, n);
    n = (long long)NLc * Ec * Ec;
    cvt_bf16<<<(int)((n + 255) / 256), 256, 0, stream>>>(Wo, wob, n);
    n = (long long)NLc * DFFc * Ec;
    cvt_bf16<<<(int)((n + 255) / 256), 256, 0, stream>>>(W1, w1b, n);
    n = (long long)NLc * Ec * DFFc;
    cvt_bf16<<<(int)((n + 255) / 256), 256, 0, stream>>>(W2, w2b, n);
  }
  prep_R<<<dim3(Lc / 64, Lc), 256, 0, stream>>>(pos, typ, Rb, Rt);
  init_x<<<LB * Ec / 256, 256, 0, stream>>>(src, x, xb);

  for (int i = 0; i < NLc; i++) {
    const bf16* Wi_b = wib + (size_t)i * 3 * Ec * Ec;
    const bf16* Wo_b = wob + (size_t)i * Ec * Ec;
    const bf16* W1_b = w1b + (size_t)i * DFFc * Ec;
    const bf16* W2_b = w2b + (size_t)i * Ec * DFFc;

    // QKV projection: P = xb @ Wi^T + bi   [4096, 3072]
    gemm_bt128d<false, false, false><<<dim3(LB / 128, 3 * Ec / 128, 1), 256, 0, stream>>>(
        LB, 3 * Ec, Ec, xb, Ec, 0, Wi_b, Ec, 0, P, 3 * Ec, 0, bi + (size_t)i * 3 * Ec);
    split_qk<<<LB * Ec / 256, 256, 0, stream>>>(P, q, k);
    transpose_v<<<dim3(Lc / 64, BHc), 256, 0, stream>>>(P, vt);

    // scores = q @ k^T  (batched over bh)   [P dead from here]
    gemm_bt<false, false, false><<<dim3(Lc / 128, Lc / 64, BHc), 256, 0, stream>>>(
        Lc, Lc, HDc, q, HDc, (long long)Lc * HDc, k, HDc, (long long)Lc * HDc,
        scores, Lc, (long long)Lc * Lc, nullptr);
    // scores += q_l @ R_l^T  (batched over l)
    gemm_bt<true, false, false><<<dim3(1, Lc / 64, Lc), 256, 0, stream>>>(
        BHc, Lc, HDc, q, Lc * HDc, (long long)HDc, Rb, HDc, (long long)Lc * HDc,
        scores, Lc * Lc, (long long)Lc, nullptr);

    // softmax, probs bf16 in-place over scores (row stride 1024 bf16 elements)
    softmax_rows<<<BHc * Lc / 4, 256, 0, stream>>>(scores, probs);

    // ao2 = probs @ v  (v^T stored => B^T-form; batched over bh)
    gemm_bt<false, false, false><<<dim3(Lc / 128, 1, BHc), 256, 0, stream>>>(
        Lc, HDc, Lc, probs, 1024, (long long)Lc * 1024, vt, Lc, (long long)HDc * Lc,
        ao2, HDc, (long long)Lc * HDc, nullptr);
    // ao2 += probs_l @ R_l  (R^T stored => B^T-form; batched over l)
    gemm_bt<true, false, false><<<dim3(1, 1, Lc), 256, 0, stream>>>(
        BHc, HDc, Lc, probs, Lc * 1024, (long long)1024, Rt, Lc, (long long)HDc * Lc,
        ao2, Lc * HDc, (long long)HDc, nullptr);

    merge_ao<<<BHc * Lc * HDc / 256, 256, 0, stream>>>(ao2, aob);

    // output projection: c1 = aob @ Wo^T + bo   [ao2 dead; c1 aliases it]
    gemm_bt128d<false, false, false><<<dim3(LB / 128, Ec / 128, 1), 256, 0, stream>>>(
        LB, Ec, Ec, aob, Ec, 0, Wo_b, Ec, 0, c1, Ec, 0, bo + (size_t)i * Ec);
    add_ln<<<LB, 256, 0, stream>>>(x, c1, g1 + (size_t)i * Ec, be1 + (size_t)i * Ec, x, xb);

    // ffn1: hb = gelu(xb @ W1^T + b1)  bf16 out   [probs dead; hb aliases U]
    gemm_bt128d<false, true, true><<<dim3(LB / 128, DFFc / 128, 1), 256, 0, stream>>>(
        LB, DFFc, Ec, xb, Ec, 0, W1_b, Ec, 0, hb, DFFc, 0, b1 + (size_t)i * DFFc);
    // ffn2: c1 = hb @ W2^T + b2
    gemm_bt128d<false, false, false><<<dim3(LB / 128, Ec / 128, 1), 256, 0, stream>>>(
        LB, Ec, DFFc, hb, DFFc, 0, W2_b, DFFc, 0, c1, Ec, 0, b2 + (size_t)i * Ec);

    float* outF = (i == NLc - 1) ? out : x;
    add_ln<<<LB, 256, 0, stream>>>(x, c1, g2 + (size_t)i * Ec, be2 + (size_t)i * Ec, outF, xb);
  }
}

// Round 4
// 1213.725 us; speedup vs baseline: 1.0898x; 1.0620x over previous
//
#include <hip/hip_runtime.h>
#include <hip/hip_bf16.h>
#include <math.h>

// TransformerEncoder (Shaw relative attention), MI355X gfx950.
// All GEMMs: C = A @ B^T, A[M,K], B[N,K] row-major, bf16 MFMA 16x16x32, fp32 acc.
// R = pos + typ folded once; V and R also stored transposed so every GEMM is B^T-form.
// This round: XOR-swizzled LDS (both-sides, rule #21) on the double-buffered
// 128x128 GEMM. global_load_lds dest stays LINEAR; the global SOURCE column is
// pre-permuted per lane, and ds_read applies the same XOR involution. Kills the
// measured 2.5x-of-minimum bank conflict (SQ_LDS_BANK_CONFLICT 1.26e7/dispatch).
// Attention GEMMs keep the round-0 legacy 128x64 reg-staged kernel.

typedef __hip_bfloat16 bf16;
typedef short short8 __attribute__((ext_vector_type(8)));
typedef float f32x4 __attribute__((ext_vector_type(4)));

typedef __attribute__((address_space(1))) const void gvoid;
typedef __attribute__((address_space(3))) void lvoid;

constexpr int Lc = 512;      // sequence length (also S)
constexpr int Bc = 8;        // batch
constexpr int Ec = 1024;     // embed
constexpr int Hc = 16;       // heads
constexpr int HDc = 64;      // head dim
constexpr int NLc = 2;       // layers
constexpr int DFFc = 4096;   // ffn dim
constexpr int LB = Lc * Bc;  // 4096 tokens
constexpr int BHc = Bc * Hc; // 128
constexpr float EPSc = 1e-5f;

__device__ inline unsigned short f2bfu(float f) {
  union { __hip_bfloat16 h; unsigned short u; } cv;
  cv.h = __float2bfloat16(f);
  return cv.u;
}

// ---------------------------------------------------------------------------
// Double-buffered, XOR-swizzled GEMM: C[z][M,N] = A[z][M,K] @ B[z][N,K]^T
// (+bias)(+=C)(gelu). tile 128x128, BK=64, 256 threads = 4 waves (2x2),
// acc[4][4]/wave.
//
// LDS swizzle (involution, within each 128B row): byte ^= ((row&7)<<4).
//  - global_load_lds writes LINEAR (base + lane*16B, HW requirement m104);
//    lane l of chunk c covers LDS row c*8+(l>>3), colbyte (l&7)*16, so the
//    GLOBAL source column is pre-permuted: col_elems = ((l&7) ^ (l>>3))*8.
//  - ds_read swizzles: colbyte ^= ((lr&7)<<4)  (row&7 == lr&7 because all row
//    bases wr*64/wc*64/i*16 are multiples of 8).
//  Post-swizzle a wave64 ds_read_b128 covers slot = quad ^ (lr&7): 8 lanes per
//  16B slot = structural minimum -> conflict-free.
//
// Per K-step: STAGE(next buf) issued FIRST, then ds_read+MFMA on current buf,
// then ONE __syncthreads (compiler's vmcnt(0) drain lands after the MFMA work).
// M%128==0, N%128==0, K%64==0; rows 16B-aligned.
// ---------------------------------------------------------------------------
template <bool ACC, bool GELU, bool OBF>
__global__ __launch_bounds__(256) void gemm_bt128d(
    int M, int N, int K,
    const bf16* __restrict__ A, int lda, long long sAz,
    const bf16* __restrict__ Bm, int ldb, long long sBz,
    void* __restrict__ Cv, int ldc, long long sCz,
    const float* __restrict__ bias) {
  __shared__ __align__(16) bf16 As[2 * 128 * 64];
  __shared__ __align__(16) bf16 Bs[2 * 128 * 64];
  const int tid = threadIdx.x;
  const int w = tid >> 6, lane = tid & 63, quad = lane >> 4, lr = lane & 15;
  const int wr = w >> 1, wc = w & 1;
  const int m0 = blockIdx.x * 128, n0 = blockIdx.y * 128;
  const long long z = blockIdx.z;
  A += z * sAz;
  Bm += z * sBz;
  float* Cf = (float*)Cv;
  bf16* Cb = (bf16*)Cv;

  f32x4 acc[4][4];
#pragma unroll
  for (int i = 0; i < 4; i++)
#pragma unroll
    for (int j = 0; j < 4; j++) acc[i][j] = {0.f, 0.f, 0.f, 0.f};

  // staging geometry: 16 chunks of 8 rows x 64 cols per matrix; wave w owns
  // chunks w*4..w*4+3. lane covers row chunk*8+(lane>>3); global source column
  // is PRE-SWIZZLED so that the linear HW write realizes the XOR layout.
  const int rA = lane >> 3;
  const int cA = ((lane & 7) ^ (lane >> 3)) * 8;  // pre-swizzled source col (elems)

  auto STAGE = [&](int buf, int kt) {
    const int k0 = kt << 6;
#pragma unroll
    for (int t = 0; t < 4; ++t) {
      const int chunk = w * 4 + t;  // uniform per wave
      const int row = chunk * 8 + rA;
      __builtin_amdgcn_global_load_lds(
          (gvoid*)(A + (long long)(m0 + row) * lda + k0 + cA),
          (lvoid*)(As + buf * 8192 + chunk * 512), 16, 0, 0);
      __builtin_amdgcn_global_load_lds(
          (gvoid*)(Bm + (long long)(n0 + row) * ldb + k0 + cA),
          (lvoid*)(Bs + buf * 8192 + chunk * 512), 16, 0, 0);
    }
  };

  auto COMPUTE = [&](int buf) {
    const char* Ab = (const char*)(As + buf * 8192);
    const char* Bb = (const char*)(Bs + buf * 8192);
#pragma unroll
    for (int ks = 0; ks < 64; ks += 32) {
      // swizzled column byte: linear (ks*2 + quad*16) XOR'd with (row&7)<<4,
      // where row&7 == lr&7 for every fragment row read below.
      const int swzc = (ks * 2 + quad * 16) ^ ((lr & 7) << 4);
      short8 a[4], b[4];
#pragma unroll
      for (int i = 0; i < 4; i++)
        a[i] = *(const short8*)(Ab + (wr * 64 + i * 16 + lr) * 128 + swzc);
#pragma unroll
      for (int j = 0; j < 4; j++)
        b[j] = *(const short8*)(Bb + (wc * 64 + j * 16 + lr) * 128 + swzc);
#pragma unroll
      for (int i = 0; i < 4; i++)
#pragma unroll
        for (int j = 0; j < 4; j++)
          acc[i][j] = __builtin_amdgcn_mfma_f32_16x16x32_bf16(a[i], b[j], acc[i][j], 0, 0, 0);
    }
  };

  const int nt = K >> 6;
  // prologue: stage tile 0; barrier (drains vmcnt(0))
  STAGE(0, 0);
  __syncthreads();

  int cur = 0;
  for (int t = 0; t < nt - 1; ++t) {
    STAGE(cur ^ 1, t + 1);                // issue next tile's loads FIRST
    __builtin_amdgcn_sched_barrier(0);    // pin issue order (compile-time only)
    COMPUTE(cur);                         // MFMA on current buf hides load latency
    __syncthreads();                      // compiler drains vmcnt/lgkm AFTER compute
    cur ^= 1;
  }
  COMPUTE(cur);  // last tile, no prefetch

  // epilogue: D row = quad*4+r, col = lane&15 (verified gfx950 C/D layout)
#pragma unroll
  for (int i = 0; i < 4; i++) {
#pragma unroll
    for (int j = 0; j < 4; j++) {
      int col = n0 + wc * 64 + j * 16 + lr;
      float bv = bias ? bias[col] : 0.f;
#pragma unroll
      for (int r = 0; r < 4; r++) {
        int row = m0 + wr * 64 + i * 16 + quad * 4 + r;
        long long off = z * sCz + (long long)row * ldc + col;
        float v = acc[i][j][r] + bv;
        if (ACC) v += Cf[off];
        if (GELU) v = 0.5f * v * (1.f + erff(v * 0.70710678118654752f));
        if (OBF)
          Cb[off] = __float2bfloat16(v);
        else
          Cf[off] = v;
      }
    }
  }
}

// ---------------------------------------------------------------------------
// Legacy 128x64 reg-staged GEMM (padded LDS, 2-way conflicts) — attention GEMMs.
// ---------------------------------------------------------------------------
template <bool ACC, bool GELU, bool OBF>
__global__ __launch_bounds__(256) void gemm_bt(
    int M, int N, int K,
    const bf16* __restrict__ A, int lda, long long sAz,
    const bf16* __restrict__ Bm, int ldb, long long sBz,
    void* __restrict__ Cv, int ldc, long long sCz,
    const float* __restrict__ bias) {
  __shared__ __align__(16) bf16 As[128 * 72];  // +8 pad: 2-way bank aliasing only (free)
  __shared__ __align__(16) bf16 Bs[64 * 72];
  const int tid = threadIdx.x;
  const int w = tid >> 6, lane = tid & 63, quad = lane >> 4, lr = lane & 15;
  const int m0 = blockIdx.x * 128, n0 = blockIdx.y * 64;
  const long long z = blockIdx.z;
  A += z * sAz;
  Bm += z * sBz;
  float* Cf = (float*)Cv;
  bf16* Cb = (bf16*)Cv;

  f32x4 acc[2][4];
#pragma unroll
  for (int i = 0; i < 2; i++)
#pragma unroll
    for (int j = 0; j < 4; j++) acc[i][j] = {0.f, 0.f, 0.f, 0.f};

  for (int k0 = 0; k0 < K; k0 += 64) {
    // stage A 128x64
#pragma unroll
    for (int i = 0; i < 8; i++) {
      int slot = tid + i * 256;  // 2048 slots
      int r = slot >> 4, c4 = (slot & 15) << 2;
      const bf16* srcp = A + (long long)(m0 + r) * lda + k0 + c4;
      *(ushort4*)&As[r * 72 + c4] = *(const ushort4*)srcp;
    }
    // stage B 64x64
#pragma unroll
    for (int i = 0; i < 4; i++) {
      int slot = tid + i * 256;  // 1024 slots
      int r = slot >> 4, c4 = (slot & 15) << 2;
      const bf16* srcp = Bm + (long long)(n0 + r) * ldb + k0 + c4;
      *(ushort4*)&Bs[r * 72 + c4] = *(const ushort4*)srcp;
    }
    __syncthreads();
#pragma unroll
    for (int ks = 0; ks < 64; ks += 32) {
      short8 a[2], b[4];
#pragma unroll
      for (int i = 0; i < 2; i++)
        a[i] = *(const short8*)&As[(w * 32 + i * 16 + lr) * 72 + ks + quad * 8];
#pragma unroll
      for (int j = 0; j < 4; j++)
        b[j] = *(const short8*)&Bs[(j * 16 + lr) * 72 + ks + quad * 8];
#pragma unroll
      for (int i = 0; i < 2; i++)
#pragma unroll
        for (int j = 0; j < 4; j++)
          acc[i][j] = __builtin_amdgcn_mfma_f32_16x16x32_bf16(a[i], b[j], acc[i][j], 0, 0, 0);
    }
    __syncthreads();
  }

  // epilogue: D row = quad*4+r, col = lane&15 (verified gfx950 C/D layout)
#pragma unroll
  for (int i = 0; i < 2; i++) {
#pragma unroll
    for (int j = 0; j < 4; j++) {
      int col = n0 + j * 16 + lr;
      float bv = bias ? bias[col] : 0.f;
#pragma unroll
      for (int r = 0; r < 4; r++) {
        int row = m0 + w * 32 + i * 16 + quad * 4 + r;
        long long off = z * sCz + (long long)row * ldc + col;
        float v = acc[i][j][r] + bv;
        if (ACC) v += Cf[off];
        if (GELU) v = 0.5f * v * (1.f + erff(v * 0.70710678118654752f));
        if (OBF)
          Cb[off] = __float2bfloat16(v);
        else
          Cf[off] = v;
      }
    }
  }
}

// ---------------------------------------------------------------------------
// prep: fp32 -> bf16 conversion (weights)
// ---------------------------------------------------------------------------
__global__ void cvt_bf16(const float* __restrict__ in, bf16* __restrict__ out, long long n) {
  long long i = (long long)blockIdx.x * 256 + threadIdx.x;
  if (i < n) out[i] = __float2bfloat16(in[i]);
}

// x = src (fp32), xb = bf16(src)
__global__ void init_x(const float* __restrict__ src, float* __restrict__ x, bf16* __restrict__ xb) {
  long long i = (long long)blockIdx.x * 256 + threadIdx.x;
  float v = src[i];
  x[i] = v;
  xb[i] = __float2bfloat16(v);
}

// R = pos + typ -> Rb[l,s,d] bf16 and Rt[l,d,s] bf16. grid (L/64 s-tiles, L), 256 thr
__global__ void prep_R(const float* __restrict__ pos, const float* __restrict__ typ,
                       bf16* __restrict__ Rb, bf16* __restrict__ Rt) {
  __shared__ __align__(16) float Ls[64 * 68];
  int l = blockIdx.y, s0 = blockIdx.x * 64;
  int tid = threadIdx.x;
#pragma unroll
  for (int i = 0; i < 4; i++) {
    int slot = tid + i * 256;
    int r = slot >> 4, c = (slot & 15) << 2;  // r = s offset, c = d
    long long off = (((long long)l) * Lc + s0 + r) * HDc + c;
    float4 a = *(const float4*)&pos[off];
    float4 b = *(const float4*)&typ[off];
    float4 s = {a.x + b.x, a.y + b.y, a.z + b.z, a.w + b.w};
    *(float4*)&Ls[r * 68 + c] = s;
    ushort4 o = {f2bfu(s.x), f2bfu(s.y), f2bfu(s.z), f2bfu(s.w)};
    *(ushort4*)&Rb[off] = o;
  }
  __syncthreads();
#pragma unroll
  for (int i = 0; i < 4; i++) {
    int slot = tid + i * 256;
    int d = slot >> 4, s4 = (slot & 15) << 2;
    ushort4 o = {f2bfu(Ls[(s4 + 0) * 68 + d]), f2bfu(Ls[(s4 + 1) * 68 + d]),
                 f2bfu(Ls[(s4 + 2) * 68 + d]), f2bfu(Ls[(s4 + 3) * 68 + d])};
    *(ushort4*)&Rt[(((long long)l) * HDc + d) * Lc + s0 + s4] = o;
  }
}

// P[L*B, 3E] -> q,k bf16 in [B,H,L,HD]; q scaled by HD^-0.5
__global__ void split_qk(const float* __restrict__ P, bf16* __restrict__ q, bf16* __restrict__ k) {
  long long idx = (long long)blockIdx.x * 256 + threadIdx.x;  // over L*B*E
  int col = idx & (Ec - 1);
  long long row = idx >> 10;  // l*B + b
  int l = (int)(row >> 3), b = (int)(row & 7);
  int h = col >> 6, d = col & 63;
  long long dst = (((long long)(b * Hc + h)) * Lc + l) * HDc + d;
  q[dst] = __float2bfloat16(P[row * 3072 + col] * 0.125f);
  k[dst] = __float2bfloat16(P[row * 3072 + Ec + col]);
}

// P v-part -> vt[b,h,d,l] bf16 via LDS transpose. grid (L/64, BH), 256 thr
__global__ void transpose_v(const float* __restrict__ P, bf16* __restrict__ vt) {
  __shared__ __align__(16) float Ls[64 * 68];
  int bh = blockIdx.y, b = bh >> 4, h = bh & 15;
  int l0 = blockIdx.x * 64;
  int tid = threadIdx.x;
#pragma unroll
  for (int i = 0; i < 4; i++) {
    int slot = tid + i * 256;
    int r = slot >> 4, c = (slot & 15) << 2;  // r = l offset, c = d
    float4 v = *(const float4*)&P[((long long)(l0 + r) * Bc + b) * 3072 + 2 * Ec + h * 64 + c];
    *(float4*)&Ls[r * 68 + c] = v;
  }
  __syncthreads();
#pragma unroll
  for (int i = 0; i < 4; i++) {
    int slot = tid + i * 256;
    int d = slot >> 4, s4 = (slot & 15) << 2;
    ushort4 o = {f2bfu(Ls[(s4 + 0) * 68 + d]), f2bfu(Ls[(s4 + 1) * 68 + d]),
                 f2bfu(Ls[(s4 + 2) * 68 + d]), f2bfu(Ls[(s4 + 3) * 68 + d])};
    *(ushort4*)&vt[(((long long)(b * Hc + h)) * HDc + d) * Lc + l0 + s4] = o;
  }
}

// softmax over rows of 512 fp32 -> bf16 probs IN-PLACE (probs row at bf16 offset
// row*1024, overlapping the same fp32 row). One wave per row, 4 rows/block.
// NOTE: no __restrict__ — S and P genuinely alias.
__global__ __launch_bounds__(256) void softmax_rows(const float* S, bf16* P) {
  int w = threadIdx.x >> 6, lane = threadIdx.x & 63;
  long long row = (long long)blockIdx.x * 4 + w;
  const float* sr = S + row * 512;
  float4 v0 = *(const float4*)(sr + lane * 4);
  float4 v1 = *(const float4*)(sr + 256 + lane * 4);
  float mx = fmaxf(fmaxf(fmaxf(v0.x, v0.y), fmaxf(v0.z, v0.w)),
                   fmaxf(fmaxf(v1.x, v1.y), fmaxf(v1.z, v1.w)));
#pragma unroll
  for (int o = 32; o; o >>= 1) mx = fmaxf(mx, __shfl_xor(mx, o, 64));
  float e[8];
  e[0] = __expf(v0.x - mx); e[1] = __expf(v0.y - mx);
  e[2] = __expf(v0.z - mx); e[3] = __expf(v0.w - mx);
  e[4] = __expf(v1.x - mx); e[5] = __expf(v1.y - mx);
  e[6] = __expf(v1.z - mx); e[7] = __expf(v1.w - mx);
  float sum = e[0] + e[1] + e[2] + e[3] + e[4] + e[5] + e[6] + e[7];
#pragma unroll
  for (int o = 32; o; o >>= 1) sum += __shfl_xor(sum, o, 64);
  float inv = 1.f / sum;
  ushort4 o0 = {f2bfu(e[0] * inv), f2bfu(e[1] * inv), f2bfu(e[2] * inv), f2bfu(e[3] * inv)};
  ushort4 o1 = {f2bfu(e[4] * inv), f2bfu(e[5] * inv), f2bfu(e[6] * inv), f2bfu(e[7] * inv)};
  *(ushort4*)(P + row * 1024 + lane * 4) = o0;
  *(ushort4*)(P + row * 1024 + 256 + lane * 4) = o1;
}

// ao2[B,H,L,HD] fp32 -> aob[(l*B+b), h*64+d] bf16
__global__ void merge_ao(const float* __restrict__ ao2, bf16* __restrict__ aob) {
  long long i = (long long)blockIdx.x * 256 + threadIdx.x;  // over B*H*L*HD
  int d = (int)(i & 63);
  long long t = i >> 6;
  int l = (int)(t & (Lc - 1));
  long long bh = t >> 9;
  int b = (int)(bh >> 4), h = (int)(bh & 15);
  aob[((long long)(l * Bc + b)) * Ec + h * 64 + d] = __float2bfloat16(ao2[i]);
}

// x_out = LN(x + c) * g + be; writes fp32 (outF) and bf16 (outB). one row/block
__global__ __launch_bounds__(256) void add_ln(const float* __restrict__ X, const float* __restrict__ Cin,
                                              const float* __restrict__ g, const float* __restrict__ be,
                                              float* __restrict__ outF, bf16* __restrict__ outB) {
  __shared__ float s_sum[4], s_sq[4];
  long long row = blockIdx.x;
  int tid = threadIdx.x;
  float4 xv = *(const float4*)&X[row * Ec + tid * 4];
  float4 cv = *(const float4*)&Cin[row * Ec + tid * 4];
  float v[4] = {xv.x + cv.x, xv.y + cv.y, xv.z + cv.z, xv.w + cv.w};
  float sm = v[0] + v[1] + v[2] + v[3];
  float sq = v[0] * v[0] + v[1] * v[1] + v[2] * v[2] + v[3] * v[3];
#pragma unroll
  for (int o = 32; o; o >>= 1) {
    sm += __shfl_xor(sm, o, 64);
    sq += __shfl_xor(sq, o, 64);
  }
  int w = tid >> 6, lane = tid & 63;
  if (lane == 0) {
    s_sum[w] = sm;
    s_sq[w] = sq;
  }
  __syncthreads();
  sm = s_sum[0] + s_sum[1] + s_sum[2] + s_sum[3];
  sq = s_sq[0] + s_sq[1] + s_sq[2] + s_sq[3];
  float mean = sm * (1.f / Ec);
  float var = sq * (1.f / Ec) - mean * mean;
  float rs = rsqrtf(var + EPSc);
#pragma unroll
  for (int e = 0; e < 4; e++) {
    int n = tid * 4 + e;
    float o = (v[e] - mean) * rs * g[n] + be[n];
    outF[row * Ec + n] = o;
    outB[row * Ec + n] = __float2bfloat16(o);
  }
}

// ---------------------------------------------------------------------------
// Workspace need (bytes), all 256B-aligned blocks:
//   U (P 50MB / scores 134MB+probs-in-place / hb 34MB):  134217728
//   x 16777216, xb 8388608, q 8388608, k 8388608, vt 8388608,
//   ao2c1 16777216, aob 8388608, Rb 33554432, Rt 33554432,
//   wib 12582912, wob 4194304, w1b 16777216, w2b 16777216
// total = 327155712 (312 MiB)
// ---------------------------------------------------------------------------
static constexpr size_t WS_NEED = 327155712;

// Fallback workspace, allocated ONCE at dlopen time (outside kernel_launch and
// outside graph capture). Used only if the harness workspace is too small.
struct GlobalWs {
  void* p = nullptr;
  GlobalWs() {
    if (hipMalloc(&p, WS_NEED) != hipSuccess) p = nullptr;
  }
};
static GlobalWs g_ws;

extern "C" void kernel_launch(void* const* d_in, const int* in_sizes, int n_in,
                              void* d_out, int out_size, void* d_ws, size_t ws_size,
                              hipStream_t stream) {
  const float* src = (const float*)d_in[0];
  const float* pos = (const float*)d_in[1];
  const float* typ = (const float*)d_in[2];
  const float* Wi = (const float*)d_in[3];
  const float* bi = (const float*)d_in[4];
  const float* Wo = (const float*)d_in[5];
  const float* bo = (const float*)d_in[6];
  const float* W1 = (const float*)d_in[7];
  const float* b1 = (const float*)d_in[8];
  const float* W2 = (const float*)d_in[9];
  const float* b2 = (const float*)d_in[10];
  const float* g1 = (const float*)d_in[11];
  const float* be1 = (const float*)d_in[12];
  const float* g2 = (const float*)d_in[13];
  const float* be2 = (const float*)d_in[14];
  float* out = (float*)d_out;
  (void)in_sizes; (void)n_in; (void)out_size;

  // Deterministic workspace choice (same every call): harness ws if big enough,
  // else the static fallback.
  char* wp = (ws_size >= WS_NEED) ? (char*)d_ws : (char*)g_ws.p;
  if (!wp) wp = (char*)d_ws;  // last resort
  auto alloc = [&](size_t bytes) {
    char* r = wp;
    wp += (bytes + 255) & ~(size_t)255;
    return r;
  };

  // Union region: P (QKV out fp32) -> scores fp32 (+ probs bf16 in-place) -> hb bf16
  char* U = alloc((size_t)BHc * Lc * Lc * 4);               // 134 MB
  float* P = (float*)U;
  float* scores = (float*)U;
  bf16* probs = (bf16*)U;                                   // row l at bf16 offset row*1024
  bf16* hb = (bf16*)U;

  float* x = (float*)alloc((size_t)LB * Ec * 4);            // residual fp32
  bf16* xb = (bf16*)alloc((size_t)LB * Ec * 2);             // LN'd bf16 for GEMMs
  bf16* q = (bf16*)alloc((size_t)BHc * Lc * HDc * 2);       // [B,H,L,HD]
  bf16* k = (bf16*)alloc((size_t)BHc * Lc * HDc * 2);
  bf16* vt = (bf16*)alloc((size_t)BHc * HDc * Lc * 2);      // [B,H,HD,L]
  float* ao2 = (float*)alloc((size_t)BHc * Lc * HDc * 4);   // attn out [B,H,L,HD]; aliased as c1
  float* c1 = ao2;                                          // proj / ffn2 out fp32 (disjoint lifetime)
  bf16* aob = (bf16*)alloc((size_t)LB * Ec * 2);            // merged [L*B, E] bf16
  bf16* Rb = (bf16*)alloc((size_t)Lc * Lc * HDc * 2);       // R[l,s,d]
  bf16* Rt = (bf16*)alloc((size_t)Lc * HDc * Lc * 2);       // R^T[l,d,s]
  bf16* wib = (bf16*)alloc((size_t)NLc * 3 * Ec * Ec * 2);
  bf16* wob = (bf16*)alloc((size_t)NLc * Ec * Ec * 2);
  bf16* w1b = (bf16*)alloc((size_t)NLc * DFFc * Ec * 2);
  bf16* w2b = (bf16*)alloc((size_t)NLc * Ec * DFFc * 2);

  // ---- prep
  {
    long long n;
    n = (long long)NLc * 3 * Ec * Ec;
    cvt_bf16<<<(int)((n + 255) / 256), 256, 0, stream>>>(Wi, wib, n);
    n = (long long)NLc * Ec * Ec;
    cvt_bf16<<<(int)((n + 255) / 256), 256, 0, stream>>>(Wo, wob, n);
    n = (long long)NLc * DFFc * Ec;
    cvt_bf16<<<(int)((n + 255) / 256), 256, 0, stream>>>(W1, w1b, n);
    n = (long long)NLc * Ec * DFFc;
    cvt_bf16<<<(int)((n + 255) / 256), 256, 0, stream>>>(W2, w2b, n);
  }
  prep_R<<<dim3(Lc / 64, Lc), 256, 0, stream>>>(pos, typ, Rb, Rt);
  init_x<<<LB * Ec / 256, 256, 0, stream>>>(src, x, xb);

  for (int i = 0; i < NLc; i++) {
    const bf16* Wi_b = wib + (size_t)i * 3 * Ec * Ec;
    const bf16* Wo_b = wob + (size_t)i * Ec * Ec;
    const bf16* W1_b = w1b + (size_t)i * DFFc * Ec;
    const bf16* W2_b = w2b + (size_t)i * Ec * DFFc;

    // QKV projection: P = xb @ Wi^T + bi   [4096, 3072]
    gemm_bt128d<false, false, false><<<dim3(LB / 128, 3 * Ec / 128, 1), 256, 0, stream>>>(
        LB, 3 * Ec, Ec, xb, Ec, 0, Wi_b, Ec, 0, P, 3 * Ec, 0, bi + (size_t)i * 3 * Ec);
    split_qk<<<LB * Ec / 256, 256, 0, stream>>>(P, q, k);
    transpose_v<<<dim3(Lc / 64, BHc), 256, 0, stream>>>(P, vt);

    // scores = q @ k^T  (batched over bh)   [P dead from here]
    gemm_bt<false, false, false><<<dim3(Lc / 128, Lc / 64, BHc), 256, 0, stream>>>(
        Lc, Lc, HDc, q, HDc, (long long)Lc * HDc, k, HDc, (long long)Lc * HDc,
        scores, Lc, (long long)Lc * Lc, nullptr);
    // scores += q_l @ R_l^T  (batched over l)
    gemm_bt<true, false, false><<<dim3(1, Lc / 64, Lc), 256, 0, stream>>>(
        BHc, Lc, HDc, q, Lc * HDc, (long long)HDc, Rb, HDc, (long long)Lc * HDc,
        scores, Lc * Lc, (long long)Lc, nullptr);

    // softmax, probs bf16 in-place over scores (row stride 1024 bf16 elements)
    softmax_rows<<<BHc * Lc / 4, 256, 0, stream>>>(scores, probs);

    // ao2 = probs @ v  (v^T stored => B^T-form; batched over bh)
    gemm_bt<false, false, false><<<dim3(Lc / 128, 1, BHc), 256, 0, stream>>>(
        Lc, HDc, Lc, probs, 1024, (long long)Lc * 1024, vt, Lc, (long long)HDc * Lc,
        ao2, HDc, (long long)Lc * HDc, nullptr);
    // ao2 += probs_l @ R_l  (R^T stored => B^T-form; batched over l)
    gemm_bt<true, false, false><<<dim3(1, 1, Lc), 256, 0, stream>>>(
        BHc, HDc, Lc, probs, Lc * 1024, (long long)1024, Rt, Lc, (long long)HDc * Lc,
        ao2, Lc * HDc, (long long)HDc, nullptr);

    merge_ao<<<BHc * Lc * HDc / 256, 256, 0, stream>>>(ao2, aob);

    // output projection: c1 = aob @ Wo^T + bo   [ao2 dead; c1 aliases it]
    gemm_bt128d<false, false, false><<<dim3(LB / 128, Ec / 128, 1), 256, 0, stream>>>(
        LB, Ec, Ec, aob, Ec, 0, Wo_b, Ec, 0, c1, Ec, 0, bo + (size_t)i * Ec);
    add_ln<<<LB, 256, 0, stream>>>(x, c1, g1 + (size_t)i * Ec, be1 + (size_t)i * Ec, x, xb);

    // ffn1: hb = gelu(xb @ W1^T + b1)  bf16 out   [probs dead; hb aliases U]
    gemm_bt128d<false, true, true><<<dim3(LB / 128, DFFc / 128, 1), 256, 0, stream>>>(
        LB, DFFc, Ec, xb, Ec, 0, W1_b, Ec, 0, hb, DFFc, 0, b1 + (size_t)i * DFFc);
    // ffn2: c1 = hb @ W2^T + b2
    gemm_bt128d<false, false, false><<<dim3(LB / 128, Ec / 128, 1), 256, 0, stream>>>(
        LB, Ec, DFFc, hb, DFFc, 0, W2_b, DFFc, 0, c1, Ec, 0, b2 + (size_t)i * Ec);

    float* outF = (i == NLc - 1) ? out : x;
    add_ln<<<LB, 256, 0, stream>>>(x, c1, g2 + (size_t)i * Ec, be2 + (size_t)i * Ec, outF, xb);
  }
}

// Round 5
// 1097.304 us; speedup vs baseline: 1.2054x; 1.1061x over previous
//
#include <hip/hip_runtime.h>
#include <hip/hip_bf16.h>
#include <math.h>

// TransformerEncoder (Shaw relative attention), MI355X gfx950.
// All GEMMs: C = A @ B^T, A[M,K], B[N,K] row-major, bf16 MFMA 16x16x32, fp32 acc.
// This round:
//  (1) T3-recipe pipelined K-loop in gemm_bt128d: ds_read frags -> STAGE next
//      (global_load_lds) -> MFMA -> asm vmcnt(0) -> raw s_barrier. The vmcnt(0)
//      sits AFTER the MFMA cluster so next-tile HBM latency hides under compute;
//      program order (reads before stage) removes the compiler's conservative
//      vmem-before-ds_read wait. XOR-swizzled LDS kept (conflicts == 0, r4).
//  (2) Split-K=2 for the two 256-block (1 block/CU) GEMMs: proj and FFN2 write
//      two fp32 partial planes (independent blocks, no atomics); add_ln4 fuses
//      partial-sum + bias + residual + LN.

typedef __hip_bfloat16 bf16;
typedef short short8 __attribute__((ext_vector_type(8)));
typedef float f32x4 __attribute__((ext_vector_type(4)));

typedef __attribute__((address_space(1))) const void gvoid;
typedef __attribute__((address_space(3))) void lvoid;

constexpr int Lc = 512;      // sequence length (also S)
constexpr int Bc = 8;        // batch
constexpr int Ec = 1024;     // embed
constexpr int Hc = 16;       // heads
constexpr int HDc = 64;      // head dim
constexpr int NLc = 2;       // layers
constexpr int DFFc = 4096;   // ffn dim
constexpr int LB = Lc * Bc;  // 4096 tokens
constexpr int BHc = Bc * Hc; // 128
constexpr float EPSc = 1e-5f;

__device__ inline unsigned short f2bfu(float f) {
  union { __hip_bfloat16 h; unsigned short u; } cv;
  cv.h = __float2bfloat16(f);
  return cv.u;
}

// ---------------------------------------------------------------------------
// Pipelined, XOR-swizzled GEMM: C[z][M,N] = A[z][M,K] @ B[z][N,K]^T
// (+bias)(+=C)(gelu). tile 128x128, BK=64, 256 threads = 4 waves (2x2),
// acc[4][4]/wave. Double-buffered LDS (2x32KB).
//
// LDS swizzle (involution within each 128B row): byte ^= ((row&7)<<4).
// global_load_lds dest LINEAR; global source column pre-permuted
// (col = ((lane&7)^(lane>>3))*8); ds_read applies the same XOR. Bank-conflict
// free (round-4 measured: SQ_LDS_BANK_CONFLICT == 0).
//
// K-loop (T3 minimum-2-phase, guide-verified structure):
//   LOAD frags from buf[cur] (ds_read, plain C++ -> compiler manages lgkm)
//   sched_barrier(0)
//   STAGE buf[cur^1] <- tile t+1 (8x global_load_lds)
//   sched_barrier(0)
//   setprio(1); 32x MFMA; setprio(0)          // loads fly under compute
//   asm vmcnt(0) ("memory" = compiler fence); sched_barrier(0)
//   s_barrier; sched_barrier(0)
// Safety: each wave drains its own 8 loads (vmcnt(0)) before the barrier, so
// all waves' stages landed before anyone reads the new buffer; ds_reads of
// iter t completed before the MFMA that consumed them (compiler lgkm), hence
// before the barrier, hence before iter t+1 overwrites that buffer.
// M%128==0, N%128==0, K%64==0, K>=128; rows 16B-aligned.
// ---------------------------------------------------------------------------
template <bool ACC, bool GELU, bool OBF>
__global__ __launch_bounds__(256) void gemm_bt128d(
    int M, int N, int K,
    const bf16* __restrict__ A, int lda, long long sAz,
    const bf16* __restrict__ Bm, int ldb, long long sBz,
    void* __restrict__ Cv, int ldc, long long sCz,
    const float* __restrict__ bias) {
  __shared__ __align__(16) bf16 As[2 * 128 * 64];
  __shared__ __align__(16) bf16 Bs[2 * 128 * 64];
  const int tid = threadIdx.x;
  const int w = tid >> 6, lane = tid & 63, quad = lane >> 4, lr = lane & 15;
  const int wr = w >> 1, wc = w & 1;
  const int m0 = blockIdx.x * 128, n0 = blockIdx.y * 128;
  const long long z = blockIdx.z;
  A += z * sAz;
  Bm += z * sBz;
  float* Cf = (float*)Cv;
  bf16* Cb = (bf16*)Cv;

  f32x4 acc[4][4];
#pragma unroll
  for (int i = 0; i < 4; i++)
#pragma unroll
    for (int j = 0; j < 4; j++) acc[i][j] = {0.f, 0.f, 0.f, 0.f};

  // staging geometry: 16 chunks of 8 rows x 64 cols per matrix; wave w owns
  // chunks w*4..w*4+3. LDS dest = chunk*512 elems (wave-uniform) + lane*16B;
  // global source column pre-swizzled to realize the XOR layout.
  const int rA = lane >> 3;
  const int cA = ((lane & 7) ^ (lane >> 3)) * 8;  // pre-swizzled source col (elems)

  auto STAGE = [&](int buf, int kt) {
    const int k0 = kt << 6;
#pragma unroll
    for (int t = 0; t < 4; ++t) {
      const int chunk = w * 4 + t;  // uniform per wave
      const int row = chunk * 8 + rA;
      __builtin_amdgcn_global_load_lds(
          (gvoid*)(A + (long long)(m0 + row) * lda + k0 + cA),
          (lvoid*)(As + buf * 8192 + chunk * 512), 16, 0, 0);
      __builtin_amdgcn_global_load_lds(
          (gvoid*)(Bm + (long long)(n0 + row) * ldb + k0 + cA),
          (lvoid*)(Bs + buf * 8192 + chunk * 512), 16, 0, 0);
    }
  };

  auto LOAD = [&](int buf, short8 (&a)[2][4], short8 (&b)[2][4]) {
    const char* Ab = (const char*)(As + buf * 8192);
    const char* Bb = (const char*)(Bs + buf * 8192);
#pragma unroll
    for (int ks2 = 0; ks2 < 2; ks2++) {
      const int swzc = (ks2 * 64 + quad * 16) ^ ((lr & 7) << 4);
#pragma unroll
      for (int i = 0; i < 4; i++)
        a[ks2][i] = *(const short8*)(Ab + (wr * 64 + i * 16 + lr) * 128 + swzc);
#pragma unroll
      for (int j = 0; j < 4; j++)
        b[ks2][j] = *(const short8*)(Bb + (wc * 64 + j * 16 + lr) * 128 + swzc);
    }
  };

  auto MMA = [&](short8 (&a)[2][4], short8 (&b)[2][4]) {
#pragma unroll
    for (int ks2 = 0; ks2 < 2; ks2++)
#pragma unroll
      for (int i = 0; i < 4; i++)
#pragma unroll
        for (int j = 0; j < 4; j++)
          acc[i][j] = __builtin_amdgcn_mfma_f32_16x16x32_bf16(a[ks2][i], b[ks2][j], acc[i][j], 0, 0, 0);
  };

  const int nt = K >> 6;
  // prologue: stage tile 0; per-wave drain; barrier
  STAGE(0, 0);
  asm volatile("s_waitcnt vmcnt(0)" ::: "memory");
  __builtin_amdgcn_sched_barrier(0);
  __builtin_amdgcn_s_barrier();
  __builtin_amdgcn_sched_barrier(0);

  int cur = 0;
  for (int t = 0; t < nt - 1; ++t) {
    short8 a[2][4], b[2][4];
    LOAD(cur, a, b);                      // ds_read current buf (before any vmem)
    __builtin_amdgcn_sched_barrier(0);
    STAGE(cur ^ 1, t + 1);                // issue next tile's loads
    __builtin_amdgcn_sched_barrier(0);
    __builtin_amdgcn_s_setprio(1);
    MMA(a, b);                            // loads fly under the MFMA cluster
    __builtin_amdgcn_s_setprio(0);
    asm volatile("s_waitcnt vmcnt(0)" ::: "memory");  // own 8 loads landed
    __builtin_amdgcn_sched_barrier(0);
    __builtin_amdgcn_s_barrier();         // all waves' loads landed
    __builtin_amdgcn_sched_barrier(0);
    cur ^= 1;
  }
  {
    short8 a[2][4], b[2][4];
    LOAD(cur, a, b);
    MMA(a, b);                            // last tile, no prefetch
  }

  // epilogue: D row = quad*4+r, col = lane&15 (verified gfx950 C/D layout)
#pragma unroll
  for (int i = 0; i < 4; i++) {
#pragma unroll
    for (int j = 0; j < 4; j++) {
      int col = n0 + wc * 64 + j * 16 + lr;
      float bv = bias ? bias[col] : 0.f;
#pragma unroll
      for (int r = 0; r < 4; r++) {
        int row = m0 + wr * 64 + i * 16 + quad * 4 + r;
        long long off = z * sCz + (long long)row * ldc + col;
        float v = acc[i][j][r] + bv;
        if (ACC) v += Cf[off];
        if (GELU) v = 0.5f * v * (1.f + erff(v * 0.70710678118654752f));
        if (OBF)
          Cb[off] = __float2bfloat16(v);
        else
          Cf[off] = v;
      }
    }
  }
}

// ---------------------------------------------------------------------------
// Legacy 128x64 reg-staged GEMM (padded LDS, 2-way conflicts) — attention GEMMs.
// ---------------------------------------------------------------------------
template <bool ACC, bool GELU, bool OBF>
__global__ __launch_bounds__(256) void gemm_bt(
    int M, int N, int K,
    const bf16* __restrict__ A, int lda, long long sAz,
    const bf16* __restrict__ Bm, int ldb, long long sBz,
    void* __restrict__ Cv, int ldc, long long sCz,
    const float* __restrict__ bias) {
  __shared__ __align__(16) bf16 As[128 * 72];  // +8 pad: 2-way bank aliasing only (free)
  __shared__ __align__(16) bf16 Bs[64 * 72];
  const int tid = threadIdx.x;
  const int w = tid >> 6, lane = tid & 63, quad = lane >> 4, lr = lane & 15;
  const int m0 = blockIdx.x * 128, n0 = blockIdx.y * 64;
  const long long z = blockIdx.z;
  A += z * sAz;
  Bm += z * sBz;
  float* Cf = (float*)Cv;
  bf16* Cb = (bf16*)Cv;

  f32x4 acc[2][4];
#pragma unroll
  for (int i = 0; i < 2; i++)
#pragma unroll
    for (int j = 0; j < 4; j++) acc[i][j] = {0.f, 0.f, 0.f, 0.f};

  for (int k0 = 0; k0 < K; k0 += 64) {
    // stage A 128x64
#pragma unroll
    for (int i = 0; i < 8; i++) {
      int slot = tid + i * 256;  // 2048 slots
      int r = slot >> 4, c4 = (slot & 15) << 2;
      const bf16* srcp = A + (long long)(m0 + r) * lda + k0 + c4;
      *(ushort4*)&As[r * 72 + c4] = *(const ushort4*)srcp;
    }
    // stage B 64x64
#pragma unroll
    for (int i = 0; i < 4; i++) {
      int slot = tid + i * 256;  // 1024 slots
      int r = slot >> 4, c4 = (slot & 15) << 2;
      const bf16* srcp = Bm + (long long)(n0 + r) * ldb + k0 + c4;
      *(ushort4*)&Bs[r * 72 + c4] = *(const ushort4*)srcp;
    }
    __syncthreads();
#pragma unroll
    for (int ks = 0; ks < 64; ks += 32) {
      short8 a[2], b[4];
#pragma unroll
      for (int i = 0; i < 2; i++)
        a[i] = *(const short8*)&As[(w * 32 + i * 16 + lr) * 72 + ks + quad * 8];
#pragma unroll
      for (int j = 0; j < 4; j++)
        b[j] = *(const short8*)&Bs[(j * 16 + lr) * 72 + ks + quad * 8];
#pragma unroll
      for (int i = 0; i < 2; i++)
#pragma unroll
        for (int j = 0; j < 4; j++)
          acc[i][j] = __builtin_amdgcn_mfma_f32_16x16x32_bf16(a[i], b[j], acc[i][j], 0, 0, 0);
    }
    __syncthreads();
  }

  // epilogue: D row = quad*4+r, col = lane&15 (verified gfx950 C/D layout)
#pragma unroll
  for (int i = 0; i < 2; i++) {
#pragma unroll
    for (int j = 0; j < 4; j++) {
      int col = n0 + j * 16 + lr;
      float bv = bias ? bias[col] : 0.f;
#pragma unroll
      for (int r = 0; r < 4; r++) {
        int row = m0 + w * 32 + i * 16 + quad * 4 + r;
        long long off = z * sCz + (long long)row * ldc + col;
        float v = acc[i][j][r] + bv;
        if (ACC) v += Cf[off];
        if (GELU) v = 0.5f * v * (1.f + erff(v * 0.70710678118654752f));
        if (OBF)
          Cb[off] = __float2bfloat16(v);
        else
          Cf[off] = v;
      }
    }
  }
}

// ---------------------------------------------------------------------------
// prep: fp32 -> bf16 conversion (weights)
// ---------------------------------------------------------------------------
__global__ void cvt_bf16(const float* __restrict__ in, bf16* __restrict__ out, long long n) {
  long long i = (long long)blockIdx.x * 256 + threadIdx.x;
  if (i < n) out[i] = __float2bfloat16(in[i]);
}

// x = src (fp32), xb = bf16(src)
__global__ void init_x(const float* __restrict__ src, float* __restrict__ x, bf16* __restrict__ xb) {
  long long i = (long long)blockIdx.x * 256 + threadIdx.x;
  float v = src[i];
  x[i] = v;
  xb[i] = __float2bfloat16(v);
}

// R = pos + typ -> Rb[l,s,d] bf16 and Rt[l,d,s] bf16. grid (L/64 s-tiles, L), 256 thr
__global__ void prep_R(const float* __restrict__ pos, const float* __restrict__ typ,
                       bf16* __restrict__ Rb, bf16* __restrict__ Rt) {
  __shared__ __align__(16) float Ls[64 * 68];
  int l = blockIdx.y, s0 = blockIdx.x * 64;
  int tid = threadIdx.x;
#pragma unroll
  for (int i = 0; i < 4; i++) {
    int slot = tid + i * 256;
    int r = slot >> 4, c = (slot & 15) << 2;  // r = s offset, c = d
    long long off = (((long long)l) * Lc + s0 + r) * HDc + c;
    float4 a = *(const float4*)&pos[off];
    float4 b = *(const float4*)&typ[off];
    float4 s = {a.x + b.x, a.y + b.y, a.z + b.z, a.w + b.w};
    *(float4*)&Ls[r * 68 + c] = s;
    ushort4 o = {f2bfu(s.x), f2bfu(s.y), f2bfu(s.z), f2bfu(s.w)};
    *(ushort4*)&Rb[off] = o;
  }
  __syncthreads();
#pragma unroll
  for (int i = 0; i < 4; i++) {
    int slot = tid + i * 256;
    int d = slot >> 4, s4 = (slot & 15) << 2;
    ushort4 o = {f2bfu(Ls[(s4 + 0) * 68 + d]), f2bfu(Ls[(s4 + 1) * 68 + d]),
                 f2bfu(Ls[(s4 + 2) * 68 + d]), f2bfu(Ls[(s4 + 3) * 68 + d])};
    *(ushort4*)&Rt[(((long long)l) * HDc + d) * Lc + s0 + s4] = o;
  }
}

// P[L*B, 3E] -> q,k bf16 in [B,H,L,HD]; q scaled by HD^-0.5
__global__ void split_qk(const float* __restrict__ P, bf16* __restrict__ q, bf16* __restrict__ k) {
  long long idx = (long long)blockIdx.x * 256 + threadIdx.x;  // over L*B*E
  int col = idx & (Ec - 1);
  long long row = idx >> 10;  // l*B + b
  int l = (int)(row >> 3), b = (int)(row & 7);
  int h = col >> 6, d = col & 63;
  long long dst = (((long long)(b * Hc + h)) * Lc + l) * HDc + d;
  q[dst] = __float2bfloat16(P[row * 3072 + col] * 0.125f);
  k[dst] = __float2bfloat16(P[row * 3072 + Ec + col]);
}

// P v-part -> vt[b,h,d,l] bf16 via LDS transpose. grid (L/64, BH), 256 thr
__global__ void transpose_v(const float* __restrict__ P, bf16* __restrict__ vt) {
  __shared__ __align__(16) float Ls[64 * 68];
  int bh = blockIdx.y, b = bh >> 4, h = bh & 15;
  int l0 = blockIdx.x * 64;
  int tid = threadIdx.x;
#pragma unroll
  for (int i = 0; i < 4; i++) {
    int slot = tid + i * 256;
    int r = slot >> 4, c = (slot & 15) << 2;  // r = l offset, c = d
    float4 v = *(const float4*)&P[((long long)(l0 + r) * Bc + b) * 3072 + 2 * Ec + h * 64 + c];
    *(float4*)&Ls[r * 68 + c] = v;
  }
  __syncthreads();
#pragma unroll
  for (int i = 0; i < 4; i++) {
    int slot = tid + i * 256;
    int d = slot >> 4, s4 = (slot & 15) << 2;
    ushort4 o = {f2bfu(Ls[(s4 + 0) * 68 + d]), f2bfu(Ls[(s4 + 1) * 68 + d]),
                 f2bfu(Ls[(s4 + 2) * 68 + d]), f2bfu(Ls[(s4 + 3) * 68 + d])};
    *(ushort4*)&vt[(((long long)(b * Hc + h)) * HDc + d) * Lc + l0 + s4] = o;
  }
}

// softmax over rows of 512 fp32 -> bf16 probs IN-PLACE (probs row at bf16 offset
// row*1024, overlapping the same fp32 row). One wave per row, 4 rows/block.
// NOTE: no __restrict__ — S and P genuinely alias.
__global__ __launch_bounds__(256) void softmax_rows(const float* S, bf16* P) {
  int w = threadIdx.x >> 6, lane = threadIdx.x & 63;
  long long row = (long long)blockIdx.x * 4 + w;
  const float* sr = S + row * 512;
  float4 v0 = *(const float4*)(sr + lane * 4);
  float4 v1 = *(const float4*)(sr + 256 + lane * 4);
  float mx = fmaxf(fmaxf(fmaxf(v0.x, v0.y), fmaxf(v0.z, v0.w)),
                   fmaxf(fmaxf(v1.x, v1.y), fmaxf(v1.z, v1.w)));
#pragma unroll
  for (int o = 32; o; o >>= 1) mx = fmaxf(mx, __shfl_xor(mx, o, 64));
  float e[8];
  e[0] = __expf(v0.x - mx); e[1] = __expf(v0.y - mx);
  e[2] = __expf(v0.z - mx); e[3] = __expf(v0.w - mx);
  e[4] = __expf(v1.x - mx); e[5] = __expf(v1.y - mx);
  e[6] = __expf(v1.z - mx); e[7] = __expf(v1.w - mx);
  float sum = e[0] + e[1] + e[2] + e[3] + e[4] + e[5] + e[6] + e[7];
#pragma unroll
  for (int o = 32; o; o >>= 1) sum += __shfl_xor(sum, o, 64);
  float inv = 1.f / sum;
  ushort4 o0 = {f2bfu(e[0] * inv), f2bfu(e[1] * inv), f2bfu(e[2] * inv), f2bfu(e[3] * inv)};
  ushort4 o1 = {f2bfu(e[4] * inv), f2bfu(e[5] * inv), f2bfu(e[6] * inv), f2bfu(e[7] * inv)};
  *(ushort4*)(P + row * 1024 + lane * 4) = o0;
  *(ushort4*)(P + row * 1024 + 256 + lane * 4) = o1;
}

// ao2[B,H,L,HD] fp32 -> aob[(l*B+b), h*64+d] bf16
__global__ void merge_ao(const float* __restrict__ ao2, bf16* __restrict__ aob) {
  long long i = (long long)blockIdx.x * 256 + threadIdx.x;  // over B*H*L*HD
  int d = (int)(i & 63);
  long long t = i >> 6;
  int l = (int)(t & (Lc - 1));
  long long bh = t >> 9;
  int b = (int)(bh >> 4), h = (int)(bh & 15);
  aob[((long long)(l * Bc + b)) * Ec + h * 64 + d] = __float2bfloat16(ao2[i]);
}

// x_out = LN(x + sum_s P[s] + bias) * g + be; fp32 (outF) and bf16 (outB) out.
// Fuses the split-K partial sum (ns planes of [LB,E] fp32, stride pstride elems)
// and the GEMM bias. one row/block, 256 thr.
__global__ __launch_bounds__(256) void add_ln4(
    const float* __restrict__ X, const float* __restrict__ Pp, long long pstride, int ns,
    const float* __restrict__ bias,
    const float* __restrict__ g, const float* __restrict__ be,
    float* __restrict__ outF, bf16* __restrict__ outB) {
  __shared__ float s_sum[4], s_sq[4];
  long long row = blockIdx.x;
  int tid = threadIdx.x;
  float4 xv = *(const float4*)&X[row * Ec + tid * 4];
  float4 bv = *(const float4*)&bias[tid * 4];
  float v[4] = {xv.x + bv.x, xv.y + bv.y, xv.z + bv.z, xv.w + bv.w};
  for (int s = 0; s < ns; ++s) {
    float4 pv = *(const float4*)&Pp[s * pstride + row * Ec + tid * 4];
    v[0] += pv.x; v[1] += pv.y; v[2] += pv.z; v[3] += pv.w;
  }
  float sm = v[0] + v[1] + v[2] + v[3];
  float sq = v[0] * v[0] + v[1] * v[1] + v[2] * v[2] + v[3] * v[3];
#pragma unroll
  for (int o = 32; o; o >>= 1) {
    sm += __shfl_xor(sm, o, 64);
    sq += __shfl_xor(sq, o, 64);
  }
  int w = tid >> 6, lane = tid & 63;
  if (lane == 0) {
    s_sum[w] = sm;
    s_sq[w] = sq;
  }
  __syncthreads();
  sm = s_sum[0] + s_sum[1] + s_sum[2] + s_sum[3];
  sq = s_sq[0] + s_sq[1] + s_sq[2] + s_sq[3];
  float mean = sm * (1.f / Ec);
  float var = sq * (1.f / Ec) - mean * mean;
  float rs = rsqrtf(var + EPSc);
#pragma unroll
  for (int e = 0; e < 4; e++) {
    int n = tid * 4 + e;
    float o = (v[e] - mean) * rs * g[n] + be[n];
    outF[row * Ec + n] = o;
    outB[row * Ec + n] = __float2bfloat16(o);
  }
}

// ---------------------------------------------------------------------------
// Workspace (312 MiB total, unchanged). U region (134 MB) lifetimes:
//   P (QKV out, 0..50MB) -> scores/probs (full region) -> [proj partials
//   34..66MB] -> hb (FFN1 out, 0..32MB) + [FFN2 partials 34..66MB]
// Partial planes: 2 x [LB,E] fp32 = 32 MB at U+34MB; consumed by add_ln4
// before the next writer of that range (stream-serial).
// ---------------------------------------------------------------------------
static constexpr size_t WS_NEED = 327155712;

// Fallback workspace, allocated ONCE at dlopen time (outside kernel_launch and
// outside graph capture). Used only if the harness workspace is too small.
struct GlobalWs {
  void* p = nullptr;
  GlobalWs() {
    if (hipMalloc(&p, WS_NEED) != hipSuccess) p = nullptr;
  }
};
static GlobalWs g_ws;

extern "C" void kernel_launch(void* const* d_in, const int* in_sizes, int n_in,
                              void* d_out, int out_size, void* d_ws, size_t ws_size,
                              hipStream_t stream) {
  const float* src = (const float*)d_in[0];
  const float* pos = (const float*)d_in[1];
  const float* typ = (const float*)d_in[2];
  const float* Wi = (const float*)d_in[3];
  const float* bi = (const float*)d_in[4];
  const float* Wo = (const float*)d_in[5];
  const float* bo = (const float*)d_in[6];
  const float* W1 = (const float*)d_in[7];
  const float* b1 = (const float*)d_in[8];
  const float* W2 = (const float*)d_in[9];
  const float* b2 = (const float*)d_in[10];
  const float* g1 = (const float*)d_in[11];
  const float* be1 = (const float*)d_in[12];
  const float* g2 = (const float*)d_in[13];
  const float* be2 = (const float*)d_in[14];
  float* out = (float*)d_out;
  (void)in_sizes; (void)n_in; (void)out_size;

  // Deterministic workspace choice (same every call): harness ws if big enough,
  // else the static fallback.
  char* wp = (ws_size >= WS_NEED) ? (char*)d_ws : (char*)g_ws.p;
  if (!wp) wp = (char*)d_ws;  // last resort
  auto alloc = [&](size_t bytes) {
    char* r = wp;
    wp += (bytes + 255) & ~(size_t)255;
    return r;
  };

  // Union region: P (QKV out fp32) -> scores fp32 (+ probs bf16 in-place) ->
  // {proj partials | hb + FFN2 partials}
  char* U = alloc((size_t)BHc * Lc * Lc * 4);               // 134 MB
  float* P = (float*)U;
  float* scores = (float*)U;
  bf16* probs = (bf16*)U;                                   // row l at bf16 offset row*1024
  bf16* hb = (bf16*)U;                                      // FFN1 out, 0..32MB
  float* part = (float*)(U + (size_t)34 * 1024 * 1024);     // 2 split-K planes, 34..66MB
  const long long PSTRIDE = (long long)LB * Ec;             // 4M elems = 16MB/plane

  float* x = (float*)alloc((size_t)LB * Ec * 4);            // residual fp32
  bf16* xb = (bf16*)alloc((size_t)LB * Ec * 2);             // LN'd bf16 for GEMMs
  bf16* q = (bf16*)alloc((size_t)BHc * Lc * HDc * 2);       // [B,H,L,HD]
  bf16* k = (bf16*)alloc((size_t)BHc * Lc * HDc * 2);
  bf16* vt = (bf16*)alloc((size_t)BHc * HDc * Lc * 2);      // [B,H,HD,L]
  float* ao2 = (float*)alloc((size_t)BHc * Lc * HDc * 4);   // attn out [B,H,L,HD]
  bf16* aob = (bf16*)alloc((size_t)LB * Ec * 2);            // merged [L*B, E] bf16
  bf16* Rb = (bf16*)alloc((size_t)Lc * Lc * HDc * 2);       // R[l,s,d]
  bf16* Rt = (bf16*)alloc((size_t)Lc * HDc * Lc * 2);       // R^T[l,d,s]
  bf16* wib = (bf16*)alloc((size_t)NLc * 3 * Ec * Ec * 2);
  bf16* wob = (bf16*)alloc((size_t)NLc * Ec * Ec * 2);
  bf16* w1b = (bf16*)alloc((size_t)NLc * DFFc * Ec * 2);
  bf16* w2b = (bf16*)alloc((size_t)NLc * Ec * DFFc * 2);

  // ---- prep
  {
    long long n;
    n = (long long)NLc * 3 * Ec * Ec;
    cvt_bf16<<<(int)((n + 255) / 256), 256, 0, stream>>>(Wi, wib, n);
    n = (long long)NLc * Ec * Ec;
    cvt_bf16<<<(int)((n + 255) / 256), 256, 0, stream>>>(Wo, wob, n);
    n = (long long)NLc * DFFc * Ec;
    cvt_bf16<<<(int)((n + 255) / 256), 256, 0, stream>>>(W1, w1b, n);
    n = (long long)NLc * Ec * DFFc;
    cvt_bf16<<<(int)((n + 255) / 256), 256, 0, stream>>>(W2, w2b, n);
  }
  prep_R<<<dim3(Lc / 64, Lc), 256, 0, stream>>>(pos, typ, Rb, Rt);
  init_x<<<LB * Ec / 256, 256, 0, stream>>>(src, x, xb);

  for (int i = 0; i < NLc; i++) {
    const bf16* Wi_b = wib + (size_t)i * 3 * Ec * Ec;
    const bf16* Wo_b = wob + (size_t)i * Ec * Ec;
    const bf16* W1_b = w1b + (size_t)i * DFFc * Ec;
    const bf16* W2_b = w2b + (size_t)i * Ec * DFFc;

    // QKV projection: P = xb @ Wi^T + bi   [4096, 3072]
    gemm_bt128d<false, false, false><<<dim3(LB / 128, 3 * Ec / 128, 1), 256, 0, stream>>>(
        LB, 3 * Ec, Ec, xb, Ec, 0, Wi_b, Ec, 0, P, 3 * Ec, 0, bi + (size_t)i * 3 * Ec);
    split_qk<<<LB * Ec / 256, 256, 0, stream>>>(P, q, k);
    transpose_v<<<dim3(Lc / 64, BHc), 256, 0, stream>>>(P, vt);

    // scores = q @ k^T  (batched over bh)   [P dead from here]
    gemm_bt<false, false, false><<<dim3(Lc / 128, Lc / 64, BHc), 256, 0, stream>>>(
        Lc, Lc, HDc, q, HDc, (long long)Lc * HDc, k, HDc, (long long)Lc * HDc,
        scores, Lc, (long long)Lc * Lc, nullptr);
    // scores += q_l @ R_l^T  (batched over l)
    gemm_bt<true, false, false><<<dim3(1, Lc / 64, Lc), 256, 0, stream>>>(
        BHc, Lc, HDc, q, Lc * HDc, (long long)HDc, Rb, HDc, (long long)Lc * HDc,
        scores, Lc * Lc, (long long)Lc, nullptr);

    // softmax, probs bf16 in-place over scores (row stride 1024 bf16 elements)
    softmax_rows<<<BHc * Lc / 4, 256, 0, stream>>>(scores, probs);

    // ao2 = probs @ v  (v^T stored => B^T-form; batched over bh)
    gemm_bt<false, false, false><<<dim3(Lc / 128, 1, BHc), 256, 0, stream>>>(
        Lc, HDc, Lc, probs, 1024, (long long)Lc * 1024, vt, Lc, (long long)HDc * Lc,
        ao2, HDc, (long long)Lc * HDc, nullptr);
    // ao2 += probs_l @ R_l  (R^T stored => B^T-form; batched over l)
    gemm_bt<true, false, false><<<dim3(1, 1, Lc), 256, 0, stream>>>(
        BHc, HDc, Lc, probs, Lc * 1024, (long long)1024, Rt, Lc, (long long)HDc * Lc,
        ao2, Lc * HDc, (long long)HDc, nullptr);

    merge_ao<<<BHc * Lc * HDc / 256, 256, 0, stream>>>(ao2, aob);

    // output projection, split-K=2: part[s] = aob @ Wo^T (cols s*512..)
    // grid (32, 8, 2) = 512 blocks (2/CU). bias folded into add_ln4.
    gemm_bt128d<false, false, false><<<dim3(LB / 128, Ec / 128, 2), 256, 0, stream>>>(
        LB, Ec, Ec / 2, aob, Ec, (long long)(Ec / 2), Wo_b, Ec, (long long)(Ec / 2),
        part, Ec, PSTRIDE, nullptr);
    add_ln4<<<LB, 256, 0, stream>>>(x, part, PSTRIDE, 2, bo + (size_t)i * Ec,
                                    g1 + (size_t)i * Ec, be1 + (size_t)i * Ec, x, xb);

    // ffn1: hb = gelu(xb @ W1^T + b1)  bf16 out   [probs dead; hb aliases U]
    gemm_bt128d<false, true, true><<<dim3(LB / 128, DFFc / 128, 1), 256, 0, stream>>>(
        LB, DFFc, Ec, xb, Ec, 0, W1_b, Ec, 0, hb, DFFc, 0, b1 + (size_t)i * DFFc);
    // ffn2, split-K=2: part[s] = hb @ W2^T (cols s*2048..)
    // grid (32, 8, 2) = 512 blocks (2/CU). bias folded into add_ln4.
    gemm_bt128d<false, false, false><<<dim3(LB / 128, Ec / 128, 2), 256, 0, stream>>>(
        LB, Ec, DFFc / 2, hb, DFFc, (long long)(DFFc / 2), W2_b, DFFc, (long long)(DFFc / 2),
        part, Ec, PSTRIDE, nullptr);

    float* outF = (i == NLc - 1) ? out : x;
    add_ln4<<<LB, 256, 0, stream>>>(x, part, PSTRIDE, 2, b2 + (size_t)i * Ec,
                                    g2 + (size_t)i * Ec, be2 + (size_t)i * Ec, outF, xb);
  }
}

// Round 6
// 1017.177 us; speedup vs baseline: 1.3004x; 1.0788x over previous
//
#include <hip/hip_runtime.h>
#include <hip/hip_bf16.h>
#include <math.h>

// TransformerEncoder (Shaw relative attention), MI355X gfx950.
// All GEMMs: C = A @ B^T, A[M,K], B[N,K] row-major, bf16 MFMA 16x16x32, fp32 acc.
// This round: attention-scores traffic cut. Order flipped to QR-first (plain
// write, no RMW), then a fused qk_softmax kernel (QK MFMA in-register + add
// QR tile + row softmax + probs bf16 write) replaces {QK gemm, softmax_rows}.
// Eliminates ~400 MB/layer of HBM traffic over the 134 MB scores buffer.
// FFN/proj keep the round-5 pipelined split-K structure (1097 us verified).

typedef __hip_bfloat16 bf16;
typedef short short8 __attribute__((ext_vector_type(8)));
typedef unsigned short ushort8 __attribute__((ext_vector_type(8)));
typedef float f32x4 __attribute__((ext_vector_type(4)));

typedef __attribute__((address_space(1))) const void gvoid;
typedef __attribute__((address_space(3))) void lvoid;

constexpr int Lc = 512;      // sequence length (also S)
constexpr int Bc = 8;        // batch
constexpr int Ec = 1024;     // embed
constexpr int Hc = 16;       // heads
constexpr int HDc = 64;      // head dim
constexpr int NLc = 2;       // layers
constexpr int DFFc = 4096;   // ffn dim
constexpr int LB = Lc * Bc;  // 4096 tokens
constexpr int BHc = Bc * Hc; // 128
constexpr float EPSc = 1e-5f;

__device__ inline unsigned short f2bfu(float f) {
  union { __hip_bfloat16 h; unsigned short u; } cv;
  cv.h = __float2bfloat16(f);
  return cv.u;
}

// ---------------------------------------------------------------------------
// Pipelined, XOR-swizzled GEMM: C[z][M,N] = A[z][M,K] @ B[z][N,K]^T
// (+bias)(+=C)(gelu). tile 128x128, BK=64, 256 threads = 4 waves (2x2),
// acc[4][4]/wave. Double-buffered LDS (2x32KB). See round-4/5 notes.
// M%128==0, N%128==0, K%64==0, K>=128; rows 16B-aligned.
// ---------------------------------------------------------------------------
template <bool ACC, bool GELU, bool OBF>
__global__ __launch_bounds__(256) void gemm_bt128d(
    int M, int N, int K,
    const bf16* __restrict__ A, int lda, long long sAz,
    const bf16* __restrict__ Bm, int ldb, long long sBz,
    void* __restrict__ Cv, int ldc, long long sCz,
    const float* __restrict__ bias) {
  __shared__ __align__(16) bf16 As[2 * 128 * 64];
  __shared__ __align__(16) bf16 Bs[2 * 128 * 64];
  const int tid = threadIdx.x;
  const int w = tid >> 6, lane = tid & 63, quad = lane >> 4, lr = lane & 15;
  const int wr = w >> 1, wc = w & 1;
  const int m0 = blockIdx.x * 128, n0 = blockIdx.y * 128;
  const long long z = blockIdx.z;
  A += z * sAz;
  Bm += z * sBz;
  float* Cf = (float*)Cv;
  bf16* Cb = (bf16*)Cv;

  f32x4 acc[4][4];
#pragma unroll
  for (int i = 0; i < 4; i++)
#pragma unroll
    for (int j = 0; j < 4; j++) acc[i][j] = {0.f, 0.f, 0.f, 0.f};

  const int rA = lane >> 3;
  const int cA = ((lane & 7) ^ (lane >> 3)) * 8;  // pre-swizzled source col (elems)

  auto STAGE = [&](int buf, int kt) {
    const int k0 = kt << 6;
#pragma unroll
    for (int t = 0; t < 4; ++t) {
      const int chunk = w * 4 + t;  // uniform per wave
      const int row = chunk * 8 + rA;
      __builtin_amdgcn_global_load_lds(
          (gvoid*)(A + (long long)(m0 + row) * lda + k0 + cA),
          (lvoid*)(As + buf * 8192 + chunk * 512), 16, 0, 0);
      __builtin_amdgcn_global_load_lds(
          (gvoid*)(Bm + (long long)(n0 + row) * ldb + k0 + cA),
          (lvoid*)(Bs + buf * 8192 + chunk * 512), 16, 0, 0);
    }
  };

  auto LOAD = [&](int buf, short8 (&a)[2][4], short8 (&b)[2][4]) {
    const char* Ab = (const char*)(As + buf * 8192);
    const char* Bb = (const char*)(Bs + buf * 8192);
#pragma unroll
    for (int ks2 = 0; ks2 < 2; ks2++) {
      const int swzc = (ks2 * 64 + quad * 16) ^ ((lr & 7) << 4);
#pragma unroll
      for (int i = 0; i < 4; i++)
        a[ks2][i] = *(const short8*)(Ab + (wr * 64 + i * 16 + lr) * 128 + swzc);
#pragma unroll
      for (int j = 0; j < 4; j++)
        b[ks2][j] = *(const short8*)(Bb + (wc * 64 + j * 16 + lr) * 128 + swzc);
    }
  };

  auto MMA = [&](short8 (&a)[2][4], short8 (&b)[2][4]) {
#pragma unroll
    for (int ks2 = 0; ks2 < 2; ks2++)
#pragma unroll
      for (int i = 0; i < 4; i++)
#pragma unroll
        for (int j = 0; j < 4; j++)
          acc[i][j] = __builtin_amdgcn_mfma_f32_16x16x32_bf16(a[ks2][i], b[ks2][j], acc[i][j], 0, 0, 0);
  };

  const int nt = K >> 6;
  STAGE(0, 0);
  asm volatile("s_waitcnt vmcnt(0)" ::: "memory");
  __builtin_amdgcn_sched_barrier(0);
  __builtin_amdgcn_s_barrier();
  __builtin_amdgcn_sched_barrier(0);

  int cur = 0;
  for (int t = 0; t < nt - 1; ++t) {
    short8 a[2][4], b[2][4];
    LOAD(cur, a, b);                      // ds_read current buf (before any vmem)
    __builtin_amdgcn_sched_barrier(0);
    STAGE(cur ^ 1, t + 1);                // issue next tile's loads
    __builtin_amdgcn_sched_barrier(0);
    __builtin_amdgcn_s_setprio(1);
    MMA(a, b);                            // loads fly under the MFMA cluster
    __builtin_amdgcn_s_setprio(0);
    asm volatile("s_waitcnt vmcnt(0)" ::: "memory");  // own 8 loads landed
    __builtin_amdgcn_sched_barrier(0);
    __builtin_amdgcn_s_barrier();         // all waves' loads landed
    __builtin_amdgcn_sched_barrier(0);
    cur ^= 1;
  }
  {
    short8 a[2][4], b[2][4];
    LOAD(cur, a, b);
    MMA(a, b);                            // last tile, no prefetch
  }

  // epilogue: D row = quad*4+r, col = lane&15 (verified gfx950 C/D layout)
#pragma unroll
  for (int i = 0; i < 4; i++) {
#pragma unroll
    for (int j = 0; j < 4; j++) {
      int col = n0 + wc * 64 + j * 16 + lr;
      float bv = bias ? bias[col] : 0.f;
#pragma unroll
      for (int r = 0; r < 4; r++) {
        int row = m0 + wr * 64 + i * 16 + quad * 4 + r;
        long long off = z * sCz + (long long)row * ldc + col;
        float v = acc[i][j][r] + bv;
        if (ACC) v += Cf[off];
        if (GELU) v = 0.5f * v * (1.f + erff(v * 0.70710678118654752f));
        if (OBF)
          Cb[off] = __float2bfloat16(v);
        else
          Cf[off] = v;
      }
    }
  }
}

// ---------------------------------------------------------------------------
// Legacy 128x64 reg-staged GEMM (padded LDS, 2-way conflicts) — QR + PV/PR.
// ---------------------------------------------------------------------------
template <bool ACC, bool GELU, bool OBF>
__global__ __launch_bounds__(256) void gemm_bt(
    int M, int N, int K,
    const bf16* __restrict__ A, int lda, long long sAz,
    const bf16* __restrict__ Bm, int ldb, long long sBz,
    void* __restrict__ Cv, int ldc, long long sCz,
    const float* __restrict__ bias) {
  __shared__ __align__(16) bf16 As[128 * 72];  // +8 pad: 2-way bank aliasing only (free)
  __shared__ __align__(16) bf16 Bs[64 * 72];
  const int tid = threadIdx.x;
  const int w = tid >> 6, lane = tid & 63, quad = lane >> 4, lr = lane & 15;
  const int m0 = blockIdx.x * 128, n0 = blockIdx.y * 64;
  const long long z = blockIdx.z;
  A += z * sAz;
  Bm += z * sBz;
  float* Cf = (float*)Cv;
  bf16* Cb = (bf16*)Cv;

  f32x4 acc[2][4];
#pragma unroll
  for (int i = 0; i < 2; i++)
#pragma unroll
    for (int j = 0; j < 4; j++) acc[i][j] = {0.f, 0.f, 0.f, 0.f};

  for (int k0 = 0; k0 < K; k0 += 64) {
    // stage A 128x64
#pragma unroll
    for (int i = 0; i < 8; i++) {
      int slot = tid + i * 256;  // 2048 slots
      int r = slot >> 4, c4 = (slot & 15) << 2;
      const bf16* srcp = A + (long long)(m0 + r) * lda + k0 + c4;
      *(ushort4*)&As[r * 72 + c4] = *(const ushort4*)srcp;
    }
    // stage B 64x64
#pragma unroll
    for (int i = 0; i < 4; i++) {
      int slot = tid + i * 256;  // 1024 slots
      int r = slot >> 4, c4 = (slot & 15) << 2;
      const bf16* srcp = Bm + (long long)(n0 + r) * ldb + k0 + c4;
      *(ushort4*)&Bs[r * 72 + c4] = *(const ushort4*)srcp;
    }
    __syncthreads();
#pragma unroll
    for (int ks = 0; ks < 64; ks += 32) {
      short8 a[2], b[4];
#pragma unroll
      for (int i = 0; i < 2; i++)
        a[i] = *(const short8*)&As[(w * 32 + i * 16 + lr) * 72 + ks + quad * 8];
#pragma unroll
      for (int j = 0; j < 4; j++)
        b[j] = *(const short8*)&Bs[(j * 16 + lr) * 72 + ks + quad * 8];
#pragma unroll
      for (int i = 0; i < 2; i++)
#pragma unroll
        for (int j = 0; j < 4; j++)
          acc[i][j] = __builtin_amdgcn_mfma_f32_16x16x32_bf16(a[i], b[j], acc[i][j], 0, 0, 0);
    }
    __syncthreads();
  }

  // epilogue: D row = quad*4+r, col = lane&15 (verified gfx950 C/D layout)
#pragma unroll
  for (int i = 0; i < 2; i++) {
#pragma unroll
    for (int j = 0; j < 4; j++) {
      int col = n0 + j * 16 + lr;
      float bv = bias ? bias[col] : 0.f;
#pragma unroll
      for (int r = 0; r < 4; r++) {
        int row = m0 + w * 32 + i * 16 + quad * 4 + r;
        long long off = z * sCz + (long long)row * ldc + col;
        float v = acc[i][j][r] + bv;
        if (ACC) v += Cf[off];
        if (GELU) v = 0.5f * v * (1.f + erff(v * 0.70710678118654752f));
        if (OBF)
          Cb[off] = __float2bfloat16(v);
        else
          Cf[off] = v;
      }
    }
  }
}

// ---------------------------------------------------------------------------
// Fused QK^T + add(QR scores) + row softmax -> probs bf16 (in-place rows).
// Grid (L/32, 1, BH), 256 thr = 4 waves. Workgroup = 32 l-rows x full s=512
// for one bh; wave w owns s-block [w*128, w*128+128).
// Reads: q,k fragments direct from global; S = precomputed QR term (fp32).
// Writes: probs bf16 at row*1024 (same in-place trick as before). All scores
// reads complete before the first __syncthreads; probs writes happen after the
// last one; rows are workgroup-exclusive -> no overlap hazard.
// ---------------------------------------------------------------------------
__global__ __launch_bounds__(256) void qk_softmax(
    const bf16* __restrict__ q, const bf16* __restrict__ kk,
    const float* S, bf16* Pr) {
  __shared__ float red[4][32];
  __shared__ __align__(16) unsigned short pbuf[32][520];  // +8 pad
  const int tid = threadIdx.x;
  const int w = tid >> 6, lane = tid & 63, quad = lane >> 4, lr = lane & 15;
  const int bh = blockIdx.z;
  const int l0 = blockIdx.x * 32;
  const int s0 = w * 128;
  const long long qbase = (long long)bh * Lc * HDc;

  f32x4 acc[2][8];
#pragma unroll
  for (int i = 0; i < 2; i++)
#pragma unroll
    for (int j = 0; j < 8; j++) acc[i][j] = {0.f, 0.f, 0.f, 0.f};

  // QK^T: 32 MFMAs, K=64 in two slices
#pragma unroll
  for (int ks2 = 0; ks2 < 2; ks2++) {
    short8 a[2], b[8];
#pragma unroll
    for (int i = 0; i < 2; i++)
      a[i] = *(const short8*)&q[qbase + (long long)(l0 + i * 16 + lr) * HDc + ks2 * 32 + quad * 8];
#pragma unroll
    for (int j = 0; j < 8; j++)
      b[j] = *(const short8*)&kk[qbase + (long long)(s0 + j * 16 + lr) * HDc + ks2 * 32 + quad * 8];
#pragma unroll
    for (int i = 0; i < 2; i++)
#pragma unroll
      for (int j = 0; j < 8; j++)
        acc[i][j] = __builtin_amdgcn_mfma_f32_16x16x32_bf16(a[i], b[j], acc[i][j], 0, 0, 0);
  }

  // add precomputed QR scores (fragment layout: row=quad*4+r, col=lr)
  const long long srow0 = (long long)bh * Lc + l0;
#pragma unroll
  for (int i = 0; i < 2; i++)
#pragma unroll
    for (int r = 0; r < 4; r++) {
      const float* sp = S + (srow0 + i * 16 + quad * 4 + r) * Lc + s0 + lr;
#pragma unroll
      for (int j = 0; j < 8; j++) acc[i][j][r] += sp[j * 16];
    }

  // row max: thread-local over j, shfl over lr (16 lanes), LDS across waves
  float mx[2][4];
#pragma unroll
  for (int i = 0; i < 2; i++)
#pragma unroll
    for (int r = 0; r < 4; r++) {
      float m = acc[i][0][r];
#pragma unroll
      for (int j = 1; j < 8; j++) m = fmaxf(m, acc[i][j][r]);
#pragma unroll
      for (int o = 8; o; o >>= 1) m = fmaxf(m, __shfl_xor(m, o, 64));
      mx[i][r] = m;
    }
  if (lr == 0) {
#pragma unroll
    for (int i = 0; i < 2; i++)
#pragma unroll
      for (int r = 0; r < 4; r++) red[w][i * 16 + quad * 4 + r] = mx[i][r];
  }
  __syncthreads();
#pragma unroll
  for (int i = 0; i < 2; i++)
#pragma unroll
    for (int r = 0; r < 4; r++) {
      int rr = i * 16 + quad * 4 + r;
      mx[i][r] = fmaxf(fmaxf(red[0][rr], red[1][rr]), fmaxf(red[2][rr], red[3][rr]));
    }
  // exp + row sum
  float sm[2][4];
#pragma unroll
  for (int i = 0; i < 2; i++)
#pragma unroll
    for (int r = 0; r < 4; r++) {
      float s = 0.f;
#pragma unroll
      for (int j = 0; j < 8; j++) {
        float e = __expf(acc[i][j][r] - mx[i][r]);
        acc[i][j][r] = e;
        s += e;
      }
#pragma unroll
      for (int o = 8; o; o >>= 1) s += __shfl_xor(s, o, 64);
      sm[i][r] = s;
    }
  __syncthreads();  // guard red reuse
  if (lr == 0) {
#pragma unroll
    for (int i = 0; i < 2; i++)
#pragma unroll
      for (int r = 0; r < 4; r++) red[w][i * 16 + quad * 4 + r] = sm[i][r];
  }
  __syncthreads();
#pragma unroll
  for (int i = 0; i < 2; i++)
#pragma unroll
    for (int r = 0; r < 4; r++) {
      int rr = i * 16 + quad * 4 + r;
      float inv = 1.f / (red[0][rr] + red[1][rr] + red[2][rr] + red[3][rr]);
#pragma unroll
      for (int j = 0; j < 8; j++)
        pbuf[rr][s0 + j * 16 + lr] = f2bfu(acc[i][j][r] * inv);
    }
  __syncthreads();
  // coalesced copy pbuf -> probs (in-place over the scores rows, bf16 stride 1024)
#pragma unroll
  for (int it = 0; it < 8; it++) {
    int slot = tid + it * 256;          // 2048 slots = 32 rows x 64 chunks
    int row = slot >> 6, c8 = (slot & 63) * 8;
    ushort8 v = *(const ushort8*)&pbuf[row][c8];
    *(ushort8*)(Pr + (srow0 + row) * 1024 + c8) = v;
  }
}

// ---------------------------------------------------------------------------
// prep: fp32 -> bf16 conversion (weights)
// ---------------------------------------------------------------------------
__global__ void cvt_bf16(const float* __restrict__ in, bf16* __restrict__ out, long long n) {
  long long i = (long long)blockIdx.x * 256 + threadIdx.x;
  if (i < n) out[i] = __float2bfloat16(in[i]);
}

// x = src (fp32), xb = bf16(src)
__global__ void init_x(const float* __restrict__ src, float* __restrict__ x, bf16* __restrict__ xb) {
  long long i = (long long)blockIdx.x * 256 + threadIdx.x;
  float v = src[i];
  x[i] = v;
  xb[i] = __float2bfloat16(v);
}

// R = pos + typ -> Rb[l,s,d] bf16 and Rt[l,d,s] bf16. grid (L/64 s-tiles, L), 256 thr
__global__ void prep_R(const float* __restrict__ pos, const float* __restrict__ typ,
                       bf16* __restrict__ Rb, bf16* __restrict__ Rt) {
  __shared__ __align__(16) float Ls[64 * 68];
  int l = blockIdx.y, s0 = blockIdx.x * 64;
  int tid = threadIdx.x;
#pragma unroll
  for (int i = 0; i < 4; i++) {
    int slot = tid + i * 256;
    int r = slot >> 4, c = (slot & 15) << 2;  // r = s offset, c = d
    long long off = (((long long)l) * Lc + s0 + r) * HDc + c;
    float4 a = *(const float4*)&pos[off];
    float4 b = *(const float4*)&typ[off];
    float4 s = {a.x + b.x, a.y + b.y, a.z + b.z, a.w + b.w};
    *(float4*)&Ls[r * 68 + c] = s;
    ushort4 o = {f2bfu(s.x), f2bfu(s.y), f2bfu(s.z), f2bfu(s.w)};
    *(ushort4*)&Rb[off] = o;
  }
  __syncthreads();
#pragma unroll
  for (int i = 0; i < 4; i++) {
    int slot = tid + i * 256;
    int d = slot >> 4, s4 = (slot & 15) << 2;
    ushort4 o = {f2bfu(Ls[(s4 + 0) * 68 + d]), f2bfu(Ls[(s4 + 1) * 68 + d]),
                 f2bfu(Ls[(s4 + 2) * 68 + d]), f2bfu(Ls[(s4 + 3) * 68 + d])};
    *(ushort4*)&Rt[(((long long)l) * HDc + d) * Lc + s0 + s4] = o;
  }
}

// P[L*B, 3E] -> q,k bf16 in [B,H,L,HD]; q scaled by HD^-0.5
__global__ void split_qk(const float* __restrict__ P, bf16* __restrict__ q, bf16* __restrict__ k) {
  long long idx = (long long)blockIdx.x * 256 + threadIdx.x;  // over L*B*E
  int col = idx & (Ec - 1);
  long long row = idx >> 10;  // l*B + b
  int l = (int)(row >> 3), b = (int)(row & 7);
  int h = col >> 6, d = col & 63;
  long long dst = (((long long)(b * Hc + h)) * Lc + l) * HDc + d;
  q[dst] = __float2bfloat16(P[row * 3072 + col] * 0.125f);
  k[dst] = __float2bfloat16(P[row * 3072 + Ec + col]);
}

// P v-part -> vt[b,h,d,l] bf16 via LDS transpose. grid (L/64, BH), 256 thr
__global__ void transpose_v(const float* __restrict__ P, bf16* __restrict__ vt) {
  __shared__ __align__(16) float Ls[64 * 68];
  int bh = blockIdx.y, b = bh >> 4, h = bh & 15;
  int l0 = blockIdx.x * 64;
  int tid = threadIdx.x;
#pragma unroll
  for (int i = 0; i < 4; i++) {
    int slot = tid + i * 256;
    int r = slot >> 4, c = (slot & 15) << 2;  // r = l offset, c = d
    float4 v = *(const float4*)&P[((long long)(l0 + r) * Bc + b) * 3072 + 2 * Ec + h * 64 + c];
    *(float4*)&Ls[r * 68 + c] = v;
  }
  __syncthreads();
#pragma unroll
  for (int i = 0; i < 4; i++) {
    int slot = tid + i * 256;
    int d = slot >> 4, s4 = (slot & 15) << 2;
    ushort4 o = {f2bfu(Ls[(s4 + 0) * 68 + d]), f2bfu(Ls[(s4 + 1) * 68 + d]),
                 f2bfu(Ls[(s4 + 2) * 68 + d]), f2bfu(Ls[(s4 + 3) * 68 + d])};
    *(ushort4*)&vt[(((long long)(b * Hc + h)) * HDc + d) * Lc + l0 + s4] = o;
  }
}

// ao2[B,H,L,HD] fp32 -> aob[(l*B+b), h*64+d] bf16
__global__ void merge_ao(const float* __restrict__ ao2, bf16* __restrict__ aob) {
  long long i = (long long)blockIdx.x * 256 + threadIdx.x;  // over B*H*L*HD
  int d = (int)(i & 63);
  long long t = i >> 6;
  int l = (int)(t & (Lc - 1));
  long long bh = t >> 9;
  int b = (int)(bh >> 4), h = (int)(bh & 15);
  aob[((long long)(l * Bc + b)) * Ec + h * 64 + d] = __float2bfloat16(ao2[i]);
}

// x_out = LN(x + sum_s P[s] + bias) * g + be; fp32 (outF) and bf16 (outB) out.
__global__ __launch_bounds__(256) void add_ln4(
    const float* __restrict__ X, const float* __restrict__ Pp, long long pstride, int ns,
    const float* __restrict__ bias,
    const float* __restrict__ g, const float* __restrict__ be,
    float* __restrict__ outF, bf16* __restrict__ outB) {
  __shared__ float s_sum[4], s_sq[4];
  long long row = blockIdx.x;
  int tid = threadIdx.x;
  float4 xv = *(const float4*)&X[row * Ec + tid * 4];
  float4 bv = *(const float4*)&bias[tid * 4];
  float v[4] = {xv.x + bv.x, xv.y + bv.y, xv.z + bv.z, xv.w + bv.w};
  for (int s = 0; s < ns; ++s) {
    float4 pv = *(const float4*)&Pp[s * pstride + row * Ec + tid * 4];
    v[0] += pv.x; v[1] += pv.y; v[2] += pv.z; v[3] += pv.w;
  }
  float sm = v[0] + v[1] + v[2] + v[3];
  float sq = v[0] * v[0] + v[1] * v[1] + v[2] * v[2] + v[3] * v[3];
#pragma unroll
  for (int o = 32; o; o >>= 1) {
    sm += __shfl_xor(sm, o, 64);
    sq += __shfl_xor(sq, o, 64);
  }
  int w = tid >> 6, lane = tid & 63;
  if (lane == 0) {
    s_sum[w] = sm;
    s_sq[w] = sq;
  }
  __syncthreads();
  sm = s_sum[0] + s_sum[1] + s_sum[2] + s_sum[3];
  sq = s_sq[0] + s_sq[1] + s_sq[2] + s_sq[3];
  float mean = sm * (1.f / Ec);
  float var = sq * (1.f / Ec) - mean * mean;
  float rs = rsqrtf(var + EPSc);
#pragma unroll
  for (int e = 0; e < 4; e++) {
    int n = tid * 4 + e;
    float o = (v[e] - mean) * rs * g[n] + be[n];
    outF[row * Ec + n] = o;
    outB[row * Ec + n] = __float2bfloat16(o);
  }
}

// ---------------------------------------------------------------------------
// Workspace (312 MiB total, unchanged).
// ---------------------------------------------------------------------------
static constexpr size_t WS_NEED = 327155712;

struct GlobalWs {
  void* p = nullptr;
  GlobalWs() {
    if (hipMalloc(&p, WS_NEED) != hipSuccess) p = nullptr;
  }
};
static GlobalWs g_ws;

extern "C" void kernel_launch(void* const* d_in, const int* in_sizes, int n_in,
                              void* d_out, int out_size, void* d_ws, size_t ws_size,
                              hipStream_t stream) {
  const float* src = (const float*)d_in[0];
  const float* pos = (const float*)d_in[1];
  const float* typ = (const float*)d_in[2];
  const float* Wi = (const float*)d_in[3];
  const float* bi = (const float*)d_in[4];
  const float* Wo = (const float*)d_in[5];
  const float* bo = (const float*)d_in[6];
  const float* W1 = (const float*)d_in[7];
  const float* b1 = (const float*)d_in[8];
  const float* W2 = (const float*)d_in[9];
  const float* b2 = (const float*)d_in[10];
  const float* g1 = (const float*)d_in[11];
  const float* be1 = (const float*)d_in[12];
  const float* g2 = (const float*)d_in[13];
  const float* be2 = (const float*)d_in[14];
  float* out = (float*)d_out;
  (void)in_sizes; (void)n_in; (void)out_size;

  char* wp = (ws_size >= WS_NEED) ? (char*)d_ws : (char*)g_ws.p;
  if (!wp) wp = (char*)d_ws;  // last resort
  auto alloc = [&](size_t bytes) {
    char* r = wp;
    wp += (bytes + 255) & ~(size_t)255;
    return r;
  };

  // Union region: P (QKV out fp32) -> scores fp32 (+ probs bf16 in-place) ->
  // {hb + FFN2 partials} | proj partials
  char* U = alloc((size_t)BHc * Lc * Lc * 4);               // 134 MB
  float* P = (float*)U;
  float* scores = (float*)U;
  bf16* probs = (bf16*)U;                                   // row r at bf16 offset r*1024
  bf16* hb = (bf16*)U;                                      // FFN1 out, 0..32MB
  float* part = (float*)(U + (size_t)34 * 1024 * 1024);     // 2 split-K planes, 34..66MB
  const long long PSTRIDE = (long long)LB * Ec;             // 4M elems = 16MB/plane

  float* x = (float*)alloc((size_t)LB * Ec * 4);            // residual fp32
  bf16* xb = (bf16*)alloc((size_t)LB * Ec * 2);             // LN'd bf16 for GEMMs
  bf16* q = (bf16*)alloc((size_t)BHc * Lc * HDc * 2);       // [B,H,L,HD]
  bf16* k = (bf16*)alloc((size_t)BHc * Lc * HDc * 2);
  bf16* vt = (bf16*)alloc((size_t)BHc * HDc * Lc * 2);      // [B,H,HD,L]
  float* ao2 = (float*)alloc((size_t)BHc * Lc * HDc * 4);   // attn out [B,H,L,HD]
  bf16* aob = (bf16*)alloc((size_t)LB * Ec * 2);            // merged [L*B, E] bf16
  bf16* Rb = (bf16*)alloc((size_t)Lc * Lc * HDc * 2);       // R[l,s,d]
  bf16* Rt = (bf16*)alloc((size_t)Lc * HDc * Lc * 2);       // R^T[l,d,s]
  bf16* wib = (bf16*)alloc((size_t)NLc * 3 * Ec * Ec * 2);
  bf16* wob = (bf16*)alloc((size_t)NLc * Ec * Ec * 2);
  bf16* w1b = (bf16*)alloc((size_t)NLc * DFFc * Ec * 2);
  bf16* w2b = (bf16*)alloc((size_t)NLc * Ec * DFFc * 2);

  // ---- prep
  {
    long long n;
    n = (long long)NLc * 3 * Ec * Ec;
    cvt_bf16<<<(int)((n + 255) / 256), 256, 0, stream>>>(Wi, wib, n);
    n = (long long)NLc * Ec * Ec;
    cvt_bf16<<<(int)((n + 255) / 256), 256, 0, stream>>>(Wo, wob, n);
    n = (long long)NLc * DFFc * Ec;
    cvt_bf16<<<(int)((n + 255) / 256), 256, 0, stream>>>(W1, w1b, n);
    n = (long long)NLc * Ec * DFFc;
    cvt_bf16<<<(int)((n + 255) / 256), 256, 0, stream>>>(W2, w2b, n);
  }
  prep_R<<<dim3(Lc / 64, Lc), 256, 0, stream>>>(pos, typ, Rb, Rt);
  init_x<<<LB * Ec / 256, 256, 0, stream>>>(src, x, xb);

  for (int i = 0; i < NLc; i++) {
    const bf16* Wi_b = wib + (size_t)i * 3 * Ec * Ec;
    const bf16* Wo_b = wob + (size_t)i * Ec * Ec;
    const bf16* W1_b = w1b + (size_t)i * DFFc * Ec;
    const bf16* W2_b = w2b + (size_t)i * Ec * DFFc;

    // QKV projection: P = xb @ Wi^T + bi   [4096, 3072]
    gemm_bt128d<false, false, false><<<dim3(LB / 128, 3 * Ec / 128, 1), 256, 0, stream>>>(
        LB, 3 * Ec, Ec, xb, Ec, 0, Wi_b, Ec, 0, P, 3 * Ec, 0, bi + (size_t)i * 3 * Ec);
    split_qk<<<LB * Ec / 256, 256, 0, stream>>>(P, q, k);
    transpose_v<<<dim3(Lc / 64, BHc), 256, 0, stream>>>(P, vt);

    // scores = q_l @ R_l^T  (batched over l; PLAIN WRITE, P dead from here)
    gemm_bt<false, false, false><<<dim3(1, Lc / 64, Lc), 256, 0, stream>>>(
        BHc, Lc, HDc, q, Lc * HDc, (long long)HDc, Rb, HDc, (long long)Lc * HDc,
        scores, Lc * Lc, (long long)Lc, nullptr);

    // fused: probs = softmax(q @ k^T + scores), bf16 in-place rows
    qk_softmax<<<dim3(Lc / 32, 1, BHc), 256, 0, stream>>>(q, k, scores, probs);

    // ao2 = probs @ v  (v^T stored => B^T-form; batched over bh)
    gemm_bt<false, false, false><<<dim3(Lc / 128, 1, BHc), 256, 0, stream>>>(
        Lc, HDc, Lc, probs, 1024, (long long)Lc * 1024, vt, Lc, (long long)HDc * Lc,
        ao2, HDc, (long long)Lc * HDc, nullptr);
    // ao2 += probs_l @ R_l  (R^T stored => B^T-form; batched over l)
    gemm_bt<true, false, false><<<dim3(1, 1, Lc), 256, 0, stream>>>(
        BHc, HDc, Lc, probs, Lc * 1024, (long long)1024, Rt, Lc, (long long)HDc * Lc,
        ao2, Lc * HDc, (long long)HDc, nullptr);

    merge_ao<<<BHc * Lc * HDc / 256, 256, 0, stream>>>(ao2, aob);

    // output projection, split-K=2: part[s] = aob @ Wo^T (cols s*512..)
    gemm_bt128d<false, false, false><<<dim3(LB / 128, Ec / 128, 2), 256, 0, stream>>>(
        LB, Ec, Ec / 2, aob, Ec, (long long)(Ec / 2), Wo_b, Ec, (long long)(Ec / 2),
        part, Ec, PSTRIDE, nullptr);
    add_ln4<<<LB, 256, 0, stream>>>(x, part, PSTRIDE, 2, bo + (size_t)i * Ec,
                                    g1 + (size_t)i * Ec, be1 + (size_t)i * Ec, x, xb);

    // ffn1: hb = gelu(xb @ W1^T + b1)  bf16 out   [probs dead; hb aliases U]
    gemm_bt128d<false, true, true><<<dim3(LB / 128, DFFc / 128, 1), 256, 0, stream>>>(
        LB, DFFc, Ec, xb, Ec, 0, W1_b, Ec, 0, hb, DFFc, 0, b1 + (size_t)i * DFFc);
    // ffn2, split-K=2: part[s] = hb @ W2^T (cols s*2048..)
    gemm_bt128d<false, false, false><<<dim3(LB / 128, Ec / 128, 2), 256, 0, stream>>>(
        LB, Ec, DFFc / 2, hb, DFFc, (long long)(DFFc / 2), W2_b, DFFc, (long long)(DFFc / 2),
        part, Ec, PSTRIDE, nullptr);

    float* outF = (i == NLc - 1) ? out : x;
    add_ln4<<<LB, 256, 0, stream>>>(x, part, PSTRIDE, 2, b2 + (size_t)i * Ec,
                                    g2 + (size_t)i * Ec, be2 + (size_t)i * Ec, outF, xb);
  }
}

// Round 7
// 987.791 us; speedup vs baseline: 1.3391x; 1.0297x over previous
//
#include <hip/hip_runtime.h>
#include <hip/hip_bf16.h>
#include <math.h>

// TransformerEncoder (Shaw relative attention), MI355X gfx950.
// All GEMMs: C = A @ B^T, A[M,K], B[N,K] row-major, bf16 MFMA 16x16x32, fp32 acc.
// This round:
//  (1) FFN1 epilogue: libm erff -> Abramowitz-Stegun 7.1.26 erf (|eps|<=1.5e-7,
//      ~30x below bf16 output ulp). Kills the 46% VALUBusy epilogue wall.
//  (2) QR scores stored bf16 IN-PLACE in the probs rows (stride-1024 bf16,
//      row (bh*L+l)*1024): QR gemm writes bf16 (OBF), qk_softmax reads bf16.
//      Saves 67 MB write + 67 MB read per layer. Hazards: QR->qk stream-serial;
//      each qk workgroup reads only its own rows before overwriting them.

typedef __hip_bfloat16 bf16;
typedef short short8 __attribute__((ext_vector_type(8)));
typedef unsigned short ushort8 __attribute__((ext_vector_type(8)));
typedef float f32x4 __attribute__((ext_vector_type(4)));

typedef __attribute__((address_space(1))) const void gvoid;
typedef __attribute__((address_space(3))) void lvoid;

constexpr int Lc = 512;      // sequence length (also S)
constexpr int Bc = 8;        // batch
constexpr int Ec = 1024;     // embed
constexpr int Hc = 16;       // heads
constexpr int HDc = 64;      // head dim
constexpr int NLc = 2;       // layers
constexpr int DFFc = 4096;   // ffn dim
constexpr int LB = Lc * Bc;  // 4096 tokens
constexpr int BHc = Bc * Hc; // 128
constexpr float EPSc = 1e-5f;

__device__ inline unsigned short f2bfu(float f) {
  union { __hip_bfloat16 h; unsigned short u; } cv;
  cv.h = __float2bfloat16(f);
  return cv.u;
}

// gelu(v) = 0.5 v (1 + erf(v/sqrt2)) with A&S 7.1.26 erf: |eps| <= 1.5e-7,
// far below bf16 ulp (~4e-3 rel). ~12 VALU + __expf + rcp vs erff's ~35 ops.
__device__ inline float gelu_fast(float v) {
  float x = v * 0.70710678118654752f;
  float ax = fabsf(x);
  float t = 1.f / (1.f + 0.3275911f * ax);
  float poly = ((((1.061405429f * t - 1.453152027f) * t + 1.421413741f) * t
                 - 0.284496736f) * t + 0.254829592f) * t;
  float erfax = 1.f - poly * __expf(-ax * ax);
  float er = copysignf(erfax, x);
  return 0.5f * v * (1.f + er);
}

// ---------------------------------------------------------------------------
// Pipelined, XOR-swizzled GEMM: C[z][M,N] = A[z][M,K] @ B[z][N,K]^T
// (+bias)(+=C)(gelu). tile 128x128, BK=64, 256 threads = 4 waves (2x2),
// acc[4][4]/wave. Double-buffered LDS (2x32KB). See round-4/5 notes.
// M%128==0, N%128==0, K%64==0, K>=128; rows 16B-aligned.
// ---------------------------------------------------------------------------
template <bool ACC, bool GELU, bool OBF>
__global__ __launch_bounds__(256) void gemm_bt128d(
    int M, int N, int K,
    const bf16* __restrict__ A, int lda, long long sAz,
    const bf16* __restrict__ Bm, int ldb, long long sBz,
    void* __restrict__ Cv, int ldc, long long sCz,
    const float* __restrict__ bias) {
  __shared__ __align__(16) bf16 As[2 * 128 * 64];
  __shared__ __align__(16) bf16 Bs[2 * 128 * 64];
  const int tid = threadIdx.x;
  const int w = tid >> 6, lane = tid & 63, quad = lane >> 4, lr = lane & 15;
  const int wr = w >> 1, wc = w & 1;
  const int m0 = blockIdx.x * 128, n0 = blockIdx.y * 128;
  const long long z = blockIdx.z;
  A += z * sAz;
  Bm += z * sBz;
  float* Cf = (float*)Cv;
  bf16* Cb = (bf16*)Cv;

  f32x4 acc[4][4];
#pragma unroll
  for (int i = 0; i < 4; i++)
#pragma unroll
    for (int j = 0; j < 4; j++) acc[i][j] = {0.f, 0.f, 0.f, 0.f};

  const int rA = lane >> 3;
  const int cA = ((lane & 7) ^ (lane >> 3)) * 8;  // pre-swizzled source col (elems)

  auto STAGE = [&](int buf, int kt) {
    const int k0 = kt << 6;
#pragma unroll
    for (int t = 0; t < 4; ++t) {
      const int chunk = w * 4 + t;  // uniform per wave
      const int row = chunk * 8 + rA;
      __builtin_amdgcn_global_load_lds(
          (gvoid*)(A + (long long)(m0 + row) * lda + k0 + cA),
          (lvoid*)(As + buf * 8192 + chunk * 512), 16, 0, 0);
      __builtin_amdgcn_global_load_lds(
          (gvoid*)(Bm + (long long)(n0 + row) * ldb + k0 + cA),
          (lvoid*)(Bs + buf * 8192 + chunk * 512), 16, 0, 0);
    }
  };

  auto LOAD = [&](int buf, short8 (&a)[2][4], short8 (&b)[2][4]) {
    const char* Ab = (const char*)(As + buf * 8192);
    const char* Bb = (const char*)(Bs + buf * 8192);
#pragma unroll
    for (int ks2 = 0; ks2 < 2; ks2++) {
      const int swzc = (ks2 * 64 + quad * 16) ^ ((lr & 7) << 4);
#pragma unroll
      for (int i = 0; i < 4; i++)
        a[ks2][i] = *(const short8*)(Ab + (wr * 64 + i * 16 + lr) * 128 + swzc);
#pragma unroll
      for (int j = 0; j < 4; j++)
        b[ks2][j] = *(const short8*)(Bb + (wc * 64 + j * 16 + lr) * 128 + swzc);
    }
  };

  auto MMA = [&](short8 (&a)[2][4], short8 (&b)[2][4]) {
#pragma unroll
    for (int ks2 = 0; ks2 < 2; ks2++)
#pragma unroll
      for (int i = 0; i < 4; i++)
#pragma unroll
        for (int j = 0; j < 4; j++)
          acc[i][j] = __builtin_amdgcn_mfma_f32_16x16x32_bf16(a[ks2][i], b[ks2][j], acc[i][j], 0, 0, 0);
  };

  const int nt = K >> 6;
  STAGE(0, 0);
  asm volatile("s_waitcnt vmcnt(0)" ::: "memory");
  __builtin_amdgcn_sched_barrier(0);
  __builtin_amdgcn_s_barrier();
  __builtin_amdgcn_sched_barrier(0);

  int cur = 0;
  for (int t = 0; t < nt - 1; ++t) {
    short8 a[2][4], b[2][4];
    LOAD(cur, a, b);                      // ds_read current buf (before any vmem)
    __builtin_amdgcn_sched_barrier(0);
    STAGE(cur ^ 1, t + 1);                // issue next tile's loads
    __builtin_amdgcn_sched_barrier(0);
    __builtin_amdgcn_s_setprio(1);
    MMA(a, b);                            // loads fly under the MFMA cluster
    __builtin_amdgcn_s_setprio(0);
    asm volatile("s_waitcnt vmcnt(0)" ::: "memory");  // own 8 loads landed
    __builtin_amdgcn_sched_barrier(0);
    __builtin_amdgcn_s_barrier();         // all waves' loads landed
    __builtin_amdgcn_sched_barrier(0);
    cur ^= 1;
  }
  {
    short8 a[2][4], b[2][4];
    LOAD(cur, a, b);
    MMA(a, b);                            // last tile, no prefetch
  }

  // epilogue: D row = quad*4+r, col = lane&15 (verified gfx950 C/D layout)
#pragma unroll
  for (int i = 0; i < 4; i++) {
#pragma unroll
    for (int j = 0; j < 4; j++) {
      int col = n0 + wc * 64 + j * 16 + lr;
      float bv = bias ? bias[col] : 0.f;
#pragma unroll
      for (int r = 0; r < 4; r++) {
        int row = m0 + wr * 64 + i * 16 + quad * 4 + r;
        long long off = z * sCz + (long long)row * ldc + col;
        float v = acc[i][j][r] + bv;
        if (ACC) v += Cf[off];
        if (GELU) v = gelu_fast(v);
        if (OBF)
          Cb[off] = __float2bfloat16(v);
        else
          Cf[off] = v;
      }
    }
  }
}

// ---------------------------------------------------------------------------
// Legacy 128x64 reg-staged GEMM (padded LDS, 2-way conflicts) — QR + PV/PR.
// ---------------------------------------------------------------------------
template <bool ACC, bool GELU, bool OBF>
__global__ __launch_bounds__(256) void gemm_bt(
    int M, int N, int K,
    const bf16* __restrict__ A, int lda, long long sAz,
    const bf16* __restrict__ Bm, int ldb, long long sBz,
    void* __restrict__ Cv, int ldc, long long sCz,
    const float* __restrict__ bias) {
  __shared__ __align__(16) bf16 As[128 * 72];  // +8 pad: 2-way bank aliasing only (free)
  __shared__ __align__(16) bf16 Bs[64 * 72];
  const int tid = threadIdx.x;
  const int w = tid >> 6, lane = tid & 63, quad = lane >> 4, lr = lane & 15;
  const int m0 = blockIdx.x * 128, n0 = blockIdx.y * 64;
  const long long z = blockIdx.z;
  A += z * sAz;
  Bm += z * sBz;
  float* Cf = (float*)Cv;
  bf16* Cb = (bf16*)Cv;

  f32x4 acc[2][4];
#pragma unroll
  for (int i = 0; i < 2; i++)
#pragma unroll
    for (int j = 0; j < 4; j++) acc[i][j] = {0.f, 0.f, 0.f, 0.f};

  for (int k0 = 0; k0 < K; k0 += 64) {
    // stage A 128x64
#pragma unroll
    for (int i = 0; i < 8; i++) {
      int slot = tid + i * 256;  // 2048 slots
      int r = slot >> 4, c4 = (slot & 15) << 2;
      const bf16* srcp = A + (long long)(m0 + r) * lda + k0 + c4;
      *(ushort4*)&As[r * 72 + c4] = *(const ushort4*)srcp;
    }
    // stage B 64x64
#pragma unroll
    for (int i = 0; i < 4; i++) {
      int slot = tid + i * 256;  // 1024 slots
      int r = slot >> 4, c4 = (slot & 15) << 2;
      const bf16* srcp = Bm + (long long)(n0 + r) * ldb + k0 + c4;
      *(ushort4*)&Bs[r * 72 + c4] = *(const ushort4*)srcp;
    }
    __syncthreads();
#pragma unroll
    for (int ks = 0; ks < 64; ks += 32) {
      short8 a[2], b[4];
#pragma unroll
      for (int i = 0; i < 2; i++)
        a[i] = *(const short8*)&As[(w * 32 + i * 16 + lr) * 72 + ks + quad * 8];
#pragma unroll
      for (int j = 0; j < 4; j++)
        b[j] = *(const short8*)&Bs[(j * 16 + lr) * 72 + ks + quad * 8];
#pragma unroll
      for (int i = 0; i < 2; i++)
#pragma unroll
        for (int j = 0; j < 4; j++)
          acc[i][j] = __builtin_amdgcn_mfma_f32_16x16x32_bf16(a[i], b[j], acc[i][j], 0, 0, 0);
    }
    __syncthreads();
  }

  // epilogue: D row = quad*4+r, col = lane&15 (verified gfx950 C/D layout)
#pragma unroll
  for (int i = 0; i < 2; i++) {
#pragma unroll
    for (int j = 0; j < 4; j++) {
      int col = n0 + j * 16 + lr;
      float bv = bias ? bias[col] : 0.f;
#pragma unroll
      for (int r = 0; r < 4; r++) {
        int row = m0 + w * 32 + i * 16 + quad * 4 + r;
        long long off = z * sCz + (long long)row * ldc + col;
        float v = acc[i][j][r] + bv;
        if (ACC) v += Cf[off];
        if (GELU) v = gelu_fast(v);
        if (OBF)
          Cb[off] = __float2bfloat16(v);
        else
          Cf[off] = v;
      }
    }
  }
}

// ---------------------------------------------------------------------------
// Fused QK^T + add(QR scores, bf16) + row softmax -> probs bf16 (in-place rows).
// Grid (L/32, 1, BH), 256 thr = 4 waves. Workgroup = 32 l-rows x full s=512
// for one bh; wave w owns s-block [w*128, w*128+128).
// S is the precomputed QR term stored bf16 at row (bh*L+l)*1024 + s — the SAME
// rows probs overwrites at the end. Safe: rows are workgroup-exclusive; all S
// reads precede the first __syncthreads; probs writes follow the last one.
// ---------------------------------------------------------------------------
__global__ __launch_bounds__(256) void qk_softmax(
    const bf16* __restrict__ q, const bf16* __restrict__ kk,
    const bf16* S, bf16* Pr) {
  __shared__ float red[4][32];
  __shared__ __align__(16) unsigned short pbuf[32][520];  // +8 pad
  const int tid = threadIdx.x;
  const int w = tid >> 6, lane = tid & 63, quad = lane >> 4, lr = lane & 15;
  const int bh = blockIdx.z;
  const int l0 = blockIdx.x * 32;
  const int s0 = w * 128;
  const long long qbase = (long long)bh * Lc * HDc;

  f32x4 acc[2][8];
#pragma unroll
  for (int i = 0; i < 2; i++)
#pragma unroll
    for (int j = 0; j < 8; j++) acc[i][j] = {0.f, 0.f, 0.f, 0.f};

  // QK^T: 32 MFMAs, K=64 in two slices
#pragma unroll
  for (int ks2 = 0; ks2 < 2; ks2++) {
    short8 a[2], b[8];
#pragma unroll
    for (int i = 0; i < 2; i++)
      a[i] = *(const short8*)&q[qbase + (long long)(l0 + i * 16 + lr) * HDc + ks2 * 32 + quad * 8];
#pragma unroll
    for (int j = 0; j < 8; j++)
      b[j] = *(const short8*)&kk[qbase + (long long)(s0 + j * 16 + lr) * HDc + ks2 * 32 + quad * 8];
#pragma unroll
    for (int i = 0; i < 2; i++)
#pragma unroll
      for (int j = 0; j < 8; j++)
        acc[i][j] = __builtin_amdgcn_mfma_f32_16x16x32_bf16(a[i], b[j], acc[i][j], 0, 0, 0);
  }

  // add precomputed QR scores (bf16, fragment layout: row=quad*4+r, col=lr)
  const long long srow0 = (long long)bh * Lc + l0;
#pragma unroll
  for (int i = 0; i < 2; i++)
#pragma unroll
    for (int r = 0; r < 4; r++) {
      const bf16* sp = S + (srow0 + i * 16 + quad * 4 + r) * 1024 + s0 + lr;
#pragma unroll
      for (int j = 0; j < 8; j++) acc[i][j][r] += __bfloat162float(sp[j * 16]);
    }

  // row max: thread-local over j, shfl over lr (16 lanes), LDS across waves
  float mx[2][4];
#pragma unroll
  for (int i = 0; i < 2; i++)
#pragma unroll
    for (int r = 0; r < 4; r++) {
      float m = acc[i][0][r];
#pragma unroll
      for (int j = 1; j < 8; j++) m = fmaxf(m, acc[i][j][r]);
#pragma unroll
      for (int o = 8; o; o >>= 1) m = fmaxf(m, __shfl_xor(m, o, 64));
      mx[i][r] = m;
    }
  if (lr == 0) {
#pragma unroll
    for (int i = 0; i < 2; i++)
#pragma unroll
      for (int r = 0; r < 4; r++) red[w][i * 16 + quad * 4 + r] = mx[i][r];
  }
  __syncthreads();
#pragma unroll
  for (int i = 0; i < 2; i++)
#pragma unroll
    for (int r = 0; r < 4; r++) {
      int rr = i * 16 + quad * 4 + r;
      mx[i][r] = fmaxf(fmaxf(red[0][rr], red[1][rr]), fmaxf(red[2][rr], red[3][rr]));
    }
  // exp + row sum
  float sm[2][4];
#pragma unroll
  for (int i = 0; i < 2; i++)
#pragma unroll
    for (int r = 0; r < 4; r++) {
      float s = 0.f;
#pragma unroll
      for (int j = 0; j < 8; j++) {
        float e = __expf(acc[i][j][r] - mx[i][r]);
        acc[i][j][r] = e;
        s += e;
      }
#pragma unroll
      for (int o = 8; o; o >>= 1) s += __shfl_xor(s, o, 64);
      sm[i][r] = s;
    }
  __syncthreads();  // guard red reuse
  if (lr == 0) {
#pragma unroll
    for (int i = 0; i < 2; i++)
#pragma unroll
      for (int r = 0; r < 4; r++) red[w][i * 16 + quad * 4 + r] = sm[i][r];
  }
  __syncthreads();
#pragma unroll
  for (int i = 0; i < 2; i++)
#pragma unroll
    for (int r = 0; r < 4; r++) {
      int rr = i * 16 + quad * 4 + r;
      float inv = 1.f / (red[0][rr] + red[1][rr] + red[2][rr] + red[3][rr]);
#pragma unroll
      for (int j = 0; j < 8; j++)
        pbuf[rr][s0 + j * 16 + lr] = f2bfu(acc[i][j][r] * inv);
    }
  __syncthreads();
  // coalesced copy pbuf -> probs (in-place over the S rows, bf16 stride 1024)
#pragma unroll
  for (int it = 0; it < 8; it++) {
    int slot = tid + it * 256;          // 2048 slots = 32 rows x 64 chunks
    int row = slot >> 6, c8 = (slot & 63) * 8;
    ushort8 v = *(const ushort8*)&pbuf[row][c8];
    *(ushort8*)(Pr + (srow0 + row) * 1024 + c8) = v;
  }
}

// ---------------------------------------------------------------------------
// prep: fp32 -> bf16 conversion (weights)
// ---------------------------------------------------------------------------
__global__ void cvt_bf16(const float* __restrict__ in, bf16* __restrict__ out, long long n) {
  long long i = (long long)blockIdx.x * 256 + threadIdx.x;
  if (i < n) out[i] = __float2bfloat16(in[i]);
}

// x = src (fp32), xb = bf16(src)
__global__ void init_x(const float* __restrict__ src, float* __restrict__ x, bf16* __restrict__ xb) {
  long long i = (long long)blockIdx.x * 256 + threadIdx.x;
  float v = src[i];
  x[i] = v;
  xb[i] = __float2bfloat16(v);
}

// R = pos + typ -> Rb[l,s,d] bf16 and Rt[l,d,s] bf16. grid (L/64 s-tiles, L), 256 thr
__global__ void prep_R(const float* __restrict__ pos, const float* __restrict__ typ,
                       bf16* __restrict__ Rb, bf16* __restrict__ Rt) {
  __shared__ __align__(16) float Ls[64 * 68];
  int l = blockIdx.y, s0 = blockIdx.x * 64;
  int tid = threadIdx.x;
#pragma unroll
  for (int i = 0; i < 4; i++) {
    int slot = tid + i * 256;
    int r = slot >> 4, c = (slot & 15) << 2;  // r = s offset, c = d
    long long off = (((long long)l) * Lc + s0 + r) * HDc + c;
    float4 a = *(const float4*)&pos[off];
    float4 b = *(const float4*)&typ[off];
    float4 s = {a.x + b.x, a.y + b.y, a.z + b.z, a.w + b.w};
    *(float4*)&Ls[r * 68 + c] = s;
    ushort4 o = {f2bfu(s.x), f2bfu(s.y), f2bfu(s.z), f2bfu(s.w)};
    *(ushort4*)&Rb[off] = o;
  }
  __syncthreads();
#pragma unroll
  for (int i = 0; i < 4; i++) {
    int slot = tid + i * 256;
    int d = slot >> 4, s4 = (slot & 15) << 2;
    ushort4 o = {f2bfu(Ls[(s4 + 0) * 68 + d]), f2bfu(Ls[(s4 + 1) * 68 + d]),
                 f2bfu(Ls[(s4 + 2) * 68 + d]), f2bfu(Ls[(s4 + 3) * 68 + d])};
    *(ushort4*)&Rt[(((long long)l) * HDc + d) * Lc + s0 + s4] = o;
  }
}

// P[L*B, 3E] -> q,k bf16 in [B,H,L,HD]; q scaled by HD^-0.5
__global__ void split_qk(const float* __restrict__ P, bf16* __restrict__ q, bf16* __restrict__ k) {
  long long idx = (long long)blockIdx.x * 256 + threadIdx.x;  // over L*B*E
  int col = idx & (Ec - 1);
  long long row = idx >> 10;  // l*B + b
  int l = (int)(row >> 3), b = (int)(row & 7);
  int h = col >> 6, d = col & 63;
  long long dst = (((long long)(b * Hc + h)) * Lc + l) * HDc + d;
  q[dst] = __float2bfloat16(P[row * 3072 + col] * 0.125f);
  k[dst] = __float2bfloat16(P[row * 3072 + Ec + col]);
}

// P v-part -> vt[b,h,d,l] bf16 via LDS transpose. grid (L/64, BH), 256 thr
__global__ void transpose_v(const float* __restrict__ P, bf16* __restrict__ vt) {
  __shared__ __align__(16) float Ls[64 * 68];
  int bh = blockIdx.y, b = bh >> 4, h = bh & 15;
  int l0 = blockIdx.x * 64;
  int tid = threadIdx.x;
#pragma unroll
  for (int i = 0; i < 4; i++) {
    int slot = tid + i * 256;
    int r = slot >> 4, c = (slot & 15) << 2;  // r = l offset, c = d
    float4 v = *(const float4*)&P[((long long)(l0 + r) * Bc + b) * 3072 + 2 * Ec + h * 64 + c];
    *(float4*)&Ls[r * 68 + c] = v;
  }
  __syncthreads();
#pragma unroll
  for (int i = 0; i < 4; i++) {
    int slot = tid + i * 256;
    int d = slot >> 4, s4 = (slot & 15) << 2;
    ushort4 o = {f2bfu(Ls[(s4 + 0) * 68 + d]), f2bfu(Ls[(s4 + 1) * 68 + d]),
                 f2bfu(Ls[(s4 + 2) * 68 + d]), f2bfu(Ls[(s4 + 3) * 68 + d])};
    *(ushort4*)&vt[(((long long)(b * Hc + h)) * HDc + d) * Lc + l0 + s4] = o;
  }
}

// ao2[B,H,L,HD] fp32 -> aob[(l*B+b), h*64+d] bf16
__global__ void merge_ao(const float* __restrict__ ao2, bf16* __restrict__ aob) {
  long long i = (long long)blockIdx.x * 256 + threadIdx.x;  // over B*H*L*HD
  int d = (int)(i & 63);
  long long t = i >> 6;
  int l = (int)(t & (Lc - 1));
  long long bh = t >> 9;
  int b = (int)(bh >> 4), h = (int)(bh & 15);
  aob[((long long)(l * Bc + b)) * Ec + h * 64 + d] = __float2bfloat16(ao2[i]);
}

// x_out = LN(x + sum_s P[s] + bias) * g + be; fp32 (outF) and bf16 (outB) out.
__global__ __launch_bounds__(256) void add_ln4(
    const float* __restrict__ X, const float* __restrict__ Pp, long long pstride, int ns,
    const float* __restrict__ bias,
    const float* __restrict__ g, const float* __restrict__ be,
    float* __restrict__ outF, bf16* __restrict__ outB) {
  __shared__ float s_sum[4], s_sq[4];
  long long row = blockIdx.x;
  int tid = threadIdx.x;
  float4 xv = *(const float4*)&X[row * Ec + tid * 4];
  float4 bv = *(const float4*)&bias[tid * 4];
  float v[4] = {xv.x + bv.x, xv.y + bv.y, xv.z + bv.z, xv.w + bv.w};
  for (int s = 0; s < ns; ++s) {
    float4 pv = *(const float4*)&Pp[s * pstride + row * Ec + tid * 4];
    v[0] += pv.x; v[1] += pv.y; v[2] += pv.z; v[3] += pv.w;
  }
  float sm = v[0] + v[1] + v[2] + v[3];
  float sq = v[0] * v[0] + v[1] * v[1] + v[2] * v[2] + v[3] * v[3];
#pragma unroll
  for (int o = 32; o; o >>= 1) {
    sm += __shfl_xor(sm, o, 64);
    sq += __shfl_xor(sq, o, 64);
  }
  int w = tid >> 6, lane = tid & 63;
  if (lane == 0) {
    s_sum[w] = sm;
    s_sq[w] = sq;
  }
  __syncthreads();
  sm = s_sum[0] + s_sum[1] + s_sum[2] + s_sum[3];
  sq = s_sq[0] + s_sq[1] + s_sq[2] + s_sq[3];
  float mean = sm * (1.f / Ec);
  float var = sq * (1.f / Ec) - mean * mean;
  float rs = rsqrtf(var + EPSc);
#pragma unroll
  for (int e = 0; e < 4; e++) {
    int n = tid * 4 + e;
    float o = (v[e] - mean) * rs * g[n] + be[n];
    outF[row * Ec + n] = o;
    outB[row * Ec + n] = __float2bfloat16(o);
  }
}

// ---------------------------------------------------------------------------
// Workspace (312 MiB total, unchanged).
// ---------------------------------------------------------------------------
static constexpr size_t WS_NEED = 327155712;

struct GlobalWs {
  void* p = nullptr;
  GlobalWs() {
    if (hipMalloc(&p, WS_NEED) != hipSuccess) p = nullptr;
  }
};
static GlobalWs g_ws;

extern "C" void kernel_launch(void* const* d_in, const int* in_sizes, int n_in,
                              void* d_out, int out_size, void* d_ws, size_t ws_size,
                              hipStream_t stream) {
  const float* src = (const float*)d_in[0];
  const float* pos = (const float*)d_in[1];
  const float* typ = (const float*)d_in[2];
  const float* Wi = (const float*)d_in[3];
  const float* bi = (const float*)d_in[4];
  const float* Wo = (const float*)d_in[5];
  const float* bo = (const float*)d_in[6];
  const float* W1 = (const float*)d_in[7];
  const float* b1 = (const float*)d_in[8];
  const float* W2 = (const float*)d_in[9];
  const float* b2 = (const float*)d_in[10];
  const float* g1 = (const float*)d_in[11];
  const float* be1 = (const float*)d_in[12];
  const float* g2 = (const float*)d_in[13];
  const float* be2 = (const float*)d_in[14];
  float* out = (float*)d_out;
  (void)in_sizes; (void)n_in; (void)out_size;

  char* wp = (ws_size >= WS_NEED) ? (char*)d_ws : (char*)g_ws.p;
  if (!wp) wp = (char*)d_ws;  // last resort
  auto alloc = [&](size_t bytes) {
    char* r = wp;
    wp += (bytes + 255) & ~(size_t)255;
    return r;
  };

  // Union region: P (QKV out fp32) -> S/probs bf16 rows (stride 1024) ->
  // {hb + FFN2 partials} | proj partials
  char* U = alloc((size_t)BHc * Lc * Lc * 4);               // 134 MB
  float* P = (float*)U;
  bf16* scoresB = (bf16*)U;                                 // row (bh*L+l) at bf16 offset row*1024
  bf16* probs = (bf16*)U;                                   // same rows, in-place after softmax
  bf16* hb = (bf16*)U;                                      // FFN1 out, 0..32MB
  float* part = (float*)(U + (size_t)34 * 1024 * 1024);     // 2 split-K planes, 34..66MB
  const long long PSTRIDE = (long long)LB * Ec;             // 4M elems = 16MB/plane

  float* x = (float*)alloc((size_t)LB * Ec * 4);            // residual fp32
  bf16* xb = (bf16*)alloc((size_t)LB * Ec * 2);             // LN'd bf16 for GEMMs
  bf16* q = (bf16*)alloc((size_t)BHc * Lc * HDc * 2);       // [B,H,L,HD]
  bf16* k = (bf16*)alloc((size_t)BHc * Lc * HDc * 2);
  bf16* vt = (bf16*)alloc((size_t)BHc * HDc * Lc * 2);      // [B,H,HD,L]
  float* ao2 = (float*)alloc((size_t)BHc * Lc * HDc * 4);   // attn out [B,H,L,HD]
  bf16* aob = (bf16*)alloc((size_t)LB * Ec * 2);            // merged [L*B, E] bf16
  bf16* Rb = (bf16*)alloc((size_t)Lc * Lc * HDc * 2);       // R[l,s,d]
  bf16* Rt = (bf16*)alloc((size_t)Lc * HDc * Lc * 2);       // R^T[l,d,s]
  bf16* wib = (bf16*)alloc((size_t)NLc * 3 * Ec * Ec * 2);
  bf16* wob = (bf16*)alloc((size_t)NLc * Ec * Ec * 2);
  bf16* w1b = (bf16*)alloc((size_t)NLc * DFFc * Ec * 2);
  bf16* w2b = (bf16*)alloc((size_t)NLc * Ec * DFFc * 2);

  // ---- prep
  {
    long long n;
    n = (long long)NLc * 3 * Ec * Ec;
    cvt_bf16<<<(int)((n + 255) / 256), 256, 0, stream>>>(Wi, wib, n);
    n = (long long)NLc * Ec * Ec;
    cvt_bf16<<<(int)((n + 255) / 256), 256, 0, stream>>>(Wo, wob, n);
    n = (long long)NLc * DFFc * Ec;
    cvt_bf16<<<(int)((n + 255) / 256), 256, 0, stream>>>(W1, w1b, n);
    n = (long long)NLc * Ec * DFFc;
    cvt_bf16<<<(int)((n + 255) / 256), 256, 0, stream>>>(W2, w2b, n);
  }
  prep_R<<<dim3(Lc / 64, Lc), 256, 0, stream>>>(pos, typ, Rb, Rt);
  init_x<<<LB * Ec / 256, 256, 0, stream>>>(src, x, xb);

  for (int i = 0; i < NLc; i++) {
    const bf16* Wi_b = wib + (size_t)i * 3 * Ec * Ec;
    const bf16* Wo_b = wob + (size_t)i * Ec * Ec;
    const bf16* W1_b = w1b + (size_t)i * DFFc * Ec;
    const bf16* W2_b = w2b + (size_t)i * Ec * DFFc;

    // QKV projection: P = xb @ Wi^T + bi   [4096, 3072]
    gemm_bt128d<false, false, false><<<dim3(LB / 128, 3 * Ec / 128, 1), 256, 0, stream>>>(
        LB, 3 * Ec, Ec, xb, Ec, 0, Wi_b, Ec, 0, P, 3 * Ec, 0, bi + (size_t)i * 3 * Ec);
    split_qk<<<LB * Ec / 256, 256, 0, stream>>>(P, q, k);
    transpose_v<<<dim3(Lc / 64, BHc), 256, 0, stream>>>(P, vt);

    // S = q_l @ R_l^T  (batched over l), bf16 out into stride-1024 rows:
    // elem off = row(bh)*Lc*1024 + z(l)*1024 + col(s)   [P dead from here]
    gemm_bt<false, false, true><<<dim3(1, Lc / 64, Lc), 256, 0, stream>>>(
        BHc, Lc, HDc, q, Lc * HDc, (long long)HDc, Rb, HDc, (long long)Lc * HDc,
        scoresB, Lc * 1024, (long long)1024, nullptr);

    // fused: probs = softmax(q @ k^T + S), bf16 in-place over the same rows
    qk_softmax<<<dim3(Lc / 32, 1, BHc), 256, 0, stream>>>(q, k, scoresB, probs);

    // ao2 = probs @ v  (v^T stored => B^T-form; batched over bh)
    gemm_bt<false, false, false><<<dim3(Lc / 128, 1, BHc), 256, 0, stream>>>(
        Lc, HDc, Lc, probs, 1024, (long long)Lc * 1024, vt, Lc, (long long)HDc * Lc,
        ao2, HDc, (long long)Lc * HDc, nullptr);
    // ao2 += probs_l @ R_l  (R^T stored => B^T-form; batched over l)
    gemm_bt<true, false, false><<<dim3(1, 1, Lc), 256, 0, stream>>>(
        BHc, HDc, Lc, probs, Lc * 1024, (long long)1024, Rt, Lc, (long long)HDc * Lc,
        ao2, Lc * HDc, (long long)HDc, nullptr);

    merge_ao<<<BHc * Lc * HDc / 256, 256, 0, stream>>>(ao2, aob);

    // output projection, split-K=2: part[s] = aob @ Wo^T (cols s*512..)
    gemm_bt128d<false, false, false><<<dim3(LB / 128, Ec / 128, 2), 256, 0, stream>>>(
        LB, Ec, Ec / 2, aob, Ec, (long long)(Ec / 2), Wo_b, Ec, (long long)(Ec / 2),
        part, Ec, PSTRIDE, nullptr);
    add_ln4<<<LB, 256, 0, stream>>>(x, part, PSTRIDE, 2, bo + (size_t)i * Ec,
                                    g1 + (size_t)i * Ec, be1 + (size_t)i * Ec, x, xb);

    // ffn1: hb = gelu(xb @ W1^T + b1)  bf16 out   [probs dead; hb aliases U]
    gemm_bt128d<false, true, true><<<dim3(LB / 128, DFFc / 128, 1), 256, 0, stream>>>(
        LB, DFFc, Ec, xb, Ec, 0, W1_b, Ec, 0, hb, DFFc, 0, b1 + (size_t)i * DFFc);
    // ffn2, split-K=2: part[s] = hb @ W2^T (cols s*2048..)
    gemm_bt128d<false, false, false><<<dim3(LB / 128, Ec / 128, 2), 256, 0, stream>>>(
        LB, Ec, DFFc / 2, hb, DFFc, (long long)(DFFc / 2), W2_b, DFFc, (long long)(DFFc / 2),
        part, Ec, PSTRIDE, nullptr);

    float* outF = (i == NLc - 1) ? out : x;
    add_ln4<<<LB, 256, 0, stream>>>(x, part, PSTRIDE, 2, b2 + (size_t)i * Ec,
                                    g2 + (size_t)i * Ec, be2 + (size_t)i * Ec, outF, xb);
  }
}